// Round 15
// baseline (164.040 us; speedup 1.0000x reference)
//
#include <hip/hip_runtime.h>
#include <hip/hip_bf16.h>

#define D_MODEL 1024
#define INNER   2048
#define NPROJ   4096   // 2*INNER
#define BSZ     2
#define LSEQ    1024
#define MROWS   (BSZ*LSEQ)  // 2048

#define CHUNK 32
#define WARM  24
#define NCHK  (LSEQ / CHUNK)   // 32

using short8   = __attribute__((ext_vector_type(8))) short;
using ushort8  = __attribute__((ext_vector_type(8))) unsigned short;
using f32x4    = __attribute__((ext_vector_type(4))) float;
typedef unsigned short ushort;

#define MFMA16(A,B,Cv) __builtin_amdgcn_mfma_f32_16x16x32_bf16(A,B,Cv,0,0,0)

__device__ __forceinline__ ushort tobf(float x) {
    return (ushort)(__builtin_bit_cast(unsigned, x) >> 16);
}
__device__ __forceinline__ float frombf(ushort h) {
    return __builtin_bit_cast(float, ((unsigned)h) << 16);
}
__device__ __forceinline__ void glds16(const void* g, void* l) {
    __builtin_amdgcn_global_load_lds((const __attribute__((address_space(1))) void*)g,
                                     (__attribute__((address_space(3))) void*)l, 16, 0, 0);
}

// f32 row-major (R x K) -> bf16 hi/lo in 16x32 FRAGMENT-LINEAR subtiles:
// subtile (rt,kt) = 16 rows x 32 cols; lane l = (kchunk<<4)|row holds 8 elems.
template<int K>
__device__ __forceinline__ void split_chunk(const float* __restrict__ in,
                                            ushort* __restrict__ hi,
                                            ushort* __restrict__ lo, int c) {
    int l = c & 63, sub = c >> 6;
    constexpr int KT = K / 32;
    int kt = sub % KT, rt = sub / KT;
    const float* src = in + (size_t)(rt * 16 + (l & 15)) * K + kt * 32 + (l >> 4) * 8;
    ushort8 h, lw;
#pragma unroll
    for (int j = 0; j < 8; ++j) {
        float x = src[j];
        h[j]  = tobf(x);
        lw[j] = tobf(x - frombf(h[j]));
    }
    *reinterpret_cast<ushort8*>(&hi[(size_t)c * 8]) = h;
    *reinterpret_cast<ushort8*>(&lo[(size_t)c * 8]) = lw;
}

template<int K>
__global__ __launch_bounds__(256) void splitbf_frag(const float* __restrict__ in,
                                                    ushort* __restrict__ hi,
                                                    ushort* __restrict__ lo, int nchunks) {
    int c = blockIdx.x * 256 + threadIdx.x;
    if (c >= nchunks) return;
    split_chunk<K>(in, hi, lo, c);
}

// fused: split two K=1024 matrices (W_in and x) in one launch
__global__ __launch_bounds__(256) void splitbf2_k(
    const float* __restrict__ in1, ushort* __restrict__ hi1, ushort* __restrict__ lo1, int n1,
    const float* __restrict__ in2, ushort* __restrict__ hi2, ushort* __restrict__ lo2, int n2) {
    int c = blockIdx.x * 256 + threadIdx.x;
    if (c < n1) {
        split_chunk<D_MODEL>(in1, hi1, lo1, c);
    } else {
        int cc = c - n1;
        if (cc < n2) split_chunk<D_MODEL>(in2, hi2, lo2, cc);
    }
}

// ---------------------------------------------------------------------------
// Pipelined bf16x3 GEMM (16x16x32): C[MROWS,NCOL] = A[MROWS,K]*B[NCOL,K]^T.
// 128x128 tile, 4 waves (2Mx2N, wave tile 64x64), NBUF=3, 72KB LDS ->
// 2 WGs/CU: co-resident WGs' independent barriers overlap each other's
// stalls (m114). 8 glds/thread/tile; counted vmcnt(8) at tile boundary.
// Per K-tile: R1{MFMA hh; read bl; issue Bh,Bl} R2{MFMA hl; read al} BAR1
//             R3{MFMA lh; issue Ah,Al; vmcnt(8)} BAR2 R4{read next ah,bh}.
// All stage calls take ABSOLUTE k-tile index (t0 added by caller).
// ---------------------------------------------------------------------------
template<int NCOL, int K, int SPLITK, bool PARTIAL>
__global__ __launch_bounds__(256, 2) void gemm_pipe(
    const ushort* __restrict__ Agh, const ushort* __restrict__ Agl,
    const ushort* __restrict__ Bgh, const ushort* __restrict__ Bgl,
    float* __restrict__ C0, float* __restrict__ Crest)
{
    constexpr int BM = 128, BN = 128, NW = 4;
    constexpr int KT = K / 32;
    constexpr int NT = KT / SPLITK;
    __shared__ ushort Ah[3][BM * 32], Al[3][BM * 32];
    __shared__ ushort Bh[3][BN * 32], Bl[3][BN * 32];

    const int tid = threadIdx.x;
    const int wid = tid >> 6, lane = tid & 63;
    const int lm = lane & 15, lk = lane >> 4;

    constexpr int NTX = NCOL / BN;
    constexpr int NXY = NTX * (MROWS / BM);
    constexpr int CPX = NXY / 8;
    int lin = blockIdx.y * NTX + blockIdx.x;
    int swz = (lin & 7) * CPX + (lin >> 3);
    const int m0 = (swz / NTX) * BM, n0 = (swz % NTX) * BN;
    const int t0 = (SPLITK > 1 ? blockIdx.z : 0) * NT;
    const int wm = (wid >> 1) * 64, wn = (wid & 1) * 64;

    f32x4 acc[4][4] = {};

    auto issueB = [&](const ushort* __restrict__ src, ushort* dst, int tg) {
#pragma unroll
        for (int ci = 0; ci < 2; ++ci) {
            int s = wid + ci * NW;
            const ushort* g = src + ((size_t)((n0 >> 4) + s) * KT + tg) * 512 + lane * 8;
            glds16(g, dst + s * 512);
        }
    };
    auto issueA = [&](const ushort* __restrict__ src, ushort* dst, int tg) {
#pragma unroll
        for (int ci = 0; ci < 2; ++ci) {
            int s = wid + ci * NW;
            const ushort* g = src + ((size_t)((m0 >> 4) + s) * KT + tg) * 512 + lane * 8;
            glds16(g, dst + s * 512);
        }
    };
    auto stageTile = [&](int tg, int b) {
        issueB(Bgh, &Bh[b][0], tg);
        issueB(Bgl, &Bl[b][0], tg);
        issueA(Agh, &Ah[b][0], tg);
        issueA(Agl, &Al[b][0], tg);
    };

    // prologue: stage tiles 0,1; wait tile 0 (8 loads of tile 1 in flight)
    stageTile(t0 + 0, 0);
    stageTile(t0 + 1, 1);
    asm volatile("s_waitcnt vmcnt(8)" ::: "memory");
    __builtin_amdgcn_s_barrier();

    short8 ah[4], bh[4];
#pragma unroll
    for (int i = 0; i < 4; ++i)
        ah[i] = *reinterpret_cast<const short8*>(&Ah[0][((wm >> 4) + i) * 512 + lane * 8]);
#pragma unroll
    for (int q = 0; q < 4; ++q)
        bh[q] = *reinterpret_cast<const short8*>(&Bh[0][((wn >> 4) + q) * 512 + lane * 8]);

    int cur = 0;
    for (int t = 0; t < NT; ++t) {
        int nxt = cur + 1; if (nxt == 3) nxt = 0;
        int stg = cur + 2; if (stg >= 3) stg -= 3;
        const bool pf = (t + 2 < NT);
        short8 bl[4], al[4];

        // ---- R1: hh MFMA; read bl(cur); issue Bh,Bl prefetch ----
        asm volatile("s_waitcnt lgkmcnt(0)" ::: "memory");
        __builtin_amdgcn_sched_barrier(0);
        __builtin_amdgcn_s_setprio(1);
#pragma unroll
        for (int i = 0; i < 4; ++i)
#pragma unroll
            for (int q = 0; q < 4; ++q)
                acc[i][q] = MFMA16(ah[i], bh[q], acc[i][q]);
        __builtin_amdgcn_s_setprio(0);
#pragma unroll
        for (int q = 0; q < 4; ++q)
            bl[q] = *reinterpret_cast<const short8*>(&Bl[cur][((wn >> 4) + q) * 512 + lane * 8]);
        if (pf) {
            issueB(Bgh, &Bh[stg][0], t0 + t + 2);
            issueB(Bgl, &Bl[stg][0], t0 + t + 2);
        }

        // ---- R2: hl MFMA; read al(cur) ----
        asm volatile("s_waitcnt lgkmcnt(0)" ::: "memory");
        __builtin_amdgcn_sched_barrier(0);
        __builtin_amdgcn_s_setprio(1);
#pragma unroll
        for (int i = 0; i < 4; ++i)
#pragma unroll
            for (int q = 0; q < 4; ++q)
                acc[i][q] = MFMA16(ah[i], bl[q], acc[i][q]);
        __builtin_amdgcn_s_setprio(0);
#pragma unroll
        for (int i = 0; i < 4; ++i)
            al[i] = *reinterpret_cast<const short8*>(&Al[cur][((wm >> 4) + i) * 512 + lane * 8]);
        __builtin_amdgcn_s_barrier();   // BAR1

        // ---- R3: lh MFMA; issue A prefetch; counted vmcnt ----
        asm volatile("s_waitcnt lgkmcnt(0)" ::: "memory");
        __builtin_amdgcn_sched_barrier(0);
        __builtin_amdgcn_s_setprio(1);
#pragma unroll
        for (int i = 0; i < 4; ++i)
#pragma unroll
            for (int q = 0; q < 4; ++q)
                acc[i][q] = MFMA16(al[i], bh[q], acc[i][q]);
        __builtin_amdgcn_s_setprio(0);
        if (pf) {
            issueA(Agh, &Ah[stg][0], t0 + t + 2);
            issueA(Agl, &Al[stg][0], t0 + t + 2);
        }
        if (pf) asm volatile("s_waitcnt vmcnt(8)" ::: "memory");
        else    asm volatile("s_waitcnt vmcnt(0)" ::: "memory");
        __builtin_amdgcn_s_barrier();   // BAR2: next tile fully staged

        // ---- R4: read next tile's hh frags ----
        if (t + 1 < NT) {
#pragma unroll
            for (int i = 0; i < 4; ++i)
                ah[i] = *reinterpret_cast<const short8*>(&Ah[nxt][((wm >> 4) + i) * 512 + lane * 8]);
#pragma unroll
            for (int q = 0; q < 4; ++q)
                bh[q] = *reinterpret_cast<const short8*>(&Bh[nxt][((wn >> 4) + q) * 512 + lane * 8]);
        }
        cur = nxt;
    }

    float* C = C0;
    if constexpr (PARTIAL) {
        int kz = blockIdx.z;
        if (kz != 0) C = Crest + (size_t)(kz - 1) * MROWS * NCOL;
    }
#pragma unroll
    for (int i = 0; i < 4; ++i)
#pragma unroll
        for (int j = 0; j < 4; ++j)
#pragma unroll
            for (int r = 0; r < 4; ++r) {
                int row = m0 + wm + i * 16 + lk * 4 + r;
                int col = n0 + wn + j * 16 + lm;
                C[(size_t)row * NCOL + col] = acc[i][j][r];
            }
}

// out += sum of 3 partials (out already holds partial 0)
__global__ __launch_bounds__(256) void reduce_sk(float* __restrict__ out,
                                                 const float* __restrict__ rest) {
    constexpr size_t MN = (size_t)MROWS * D_MODEL;
    size_t i = ((size_t)blockIdx.x * 256 + threadIdx.x) * 4;
    f32x4 a = *reinterpret_cast<const f32x4*>(&out[i]);
    f32x4 b = *reinterpret_cast<const f32x4*>(&rest[i]);
    f32x4 c = *reinterpret_cast<const f32x4*>(&rest[MN + i]);
    f32x4 d = *reinterpret_cast<const f32x4*>(&rest[2 * MN + i]);
    *reinterpret_cast<f32x4*>(&out[i]) = (a + b) + (c + d);
}

// Chunk-parallel fused conv + sigmoid + scan + gate; emits yg as bf16 hi/lo
// in 16x32 fragment-linear order for GEMM2's A (K = INNER = 2048, KT = 64).
__global__ __launch_bounds__(256) void scan_kernel(
    const float* __restrict__ xp,
    const float* __restrict__ conv_w, const float* __restrict__ conv_b,
    const float* __restrict__ Aa, const float* __restrict__ Bp, const float* __restrict__ Cp,
    ushort* __restrict__ yhi, ushort* __restrict__ ylo)
{
    const int NB = INNER / 256;  // 8
    int tid = threadIdx.x;
    int bi = blockIdx.x;
    int b  = bi / (NCHK * NB);
    int r  = bi % (NCHK * NB);
    int ch = r / NB;
    int n  = (r % NB) * 256 + tid;

    float4 w = *reinterpret_cast<const float4*>(&conv_w[n * 4]);
    float cb = conv_b[n];
    float An[16], Bn[16], Cn[16], st[16];
#pragma unroll
    for (int i = 0; i < 16; i += 4) {
        float4 va = *reinterpret_cast<const float4*>(&Aa[n * 16 + i]);
        float4 vb = *reinterpret_cast<const float4*>(&Bp[n * 16 + i]);
        float4 vc = *reinterpret_cast<const float4*>(&Cp[n * 16 + i]);
        An[i]=va.x; An[i+1]=va.y; An[i+2]=va.z; An[i+3]=va.w;
        Bn[i]=vb.x; Bn[i+1]=vb.y; Bn[i+2]=vb.z; Bn[i+3]=vb.w;
        Cn[i]=vc.x; Cn[i+1]=vc.y; Cn[i+2]=vc.z; Cn[i+3]=vc.w;
    }
#pragma unroll
    for (int s = 0; s < 16; ++s) st[s] = 0.f;

    int out0 = ch * CHUNK;
    int lstart = (out0 >= WARM) ? (out0 - WARM) : 0;
    float u0 = 0.f, u1 = 0.f, u2 = 0.f;
    const float* xb = xp + (size_t)b * LSEQ * NPROJ;
    size_t fcol = (size_t)(n >> 5) * 512 + ((n >> 3) & 3) * 128 + (n & 7);

    for (int l = lstart; l < out0; l += 8) {
        float uv[8];
#pragma unroll
        for (int i = 0; i < 8; ++i)
            uv[i] = xb[(size_t)(l + i) * NPROJ + 2 * n];
#pragma unroll
        for (int i = 0; i < 8; ++i) {
            float ul = uv[i];
            float xc = cb + w.x * u0 + w.y * u1 + w.z * u2 + w.w * ul;
            u0 = u1; u1 = u2; u2 = ul;
            float d = 1.f / (1.f + __expf(-xc));
            float dxc = d * xc;
#pragma unroll
            for (int s = 0; s < 16; ++s)
                st[s] = (An[s] * d) * st[s] + Bn[s] * dxc;
        }
    }
    for (int lt = 0; lt < CHUNK; lt += 8) {
        float uv[8], gv[8];
#pragma unroll
        for (int i = 0; i < 8; ++i) {
            float2 ug = *reinterpret_cast<const float2*>(
                &xb[(size_t)(out0 + lt + i) * NPROJ + 2 * n]);
            uv[i] = ug.x; gv[i] = ug.y;
        }
#pragma unroll
        for (int i = 0; i < 8; ++i) {
            float ul = uv[i];
            float xc = cb + w.x * u0 + w.y * u1 + w.z * u2 + w.w * ul;
            u0 = u1; u1 = u2; u2 = ul;
            float d = 1.f / (1.f + __expf(-xc));
            float dxc = d * xc;
            float y0 = 0.f, y1 = 0.f, y2 = 0.f, y3 = 0.f;
#pragma unroll
            for (int s = 0; s < 16; s += 4) {
                st[s + 0] = (An[s + 0] * d) * st[s + 0] + Bn[s + 0] * dxc;
                st[s + 1] = (An[s + 1] * d) * st[s + 1] + Bn[s + 1] * dxc;
                st[s + 2] = (An[s + 2] * d) * st[s + 2] + Bn[s + 2] * dxc;
                st[s + 3] = (An[s + 3] * d) * st[s + 3] + Bn[s + 3] * dxc;
                y0 += st[s + 0] * Cn[s + 0];
                y1 += st[s + 1] * Cn[s + 1];
                y2 += st[s + 2] * Cn[s + 2];
                y3 += st[s + 3] * Cn[s + 3];
            }
            float y = (y0 + y1) + (y2 + y3);
            float g = 1.f / (1.f + __expf(-gv[i]));
            float o = y * g;
            int R = b * LSEQ + out0 + lt + i;
            size_t fi = ((size_t)(R >> 4) * 64) * 512 + fcol + (R & 15) * 8;
            ushort hh = tobf(o);
            yhi[fi] = hh;
            ylo[fi] = tobf(o - frombf(hh));
        }
    }
}

extern "C" void kernel_launch(void* const* d_in, const int* in_sizes, int n_in,
                              void* d_out, int out_size, void* d_ws, size_t ws_size,
                              hipStream_t stream) {
    const float* x      = (const float*)d_in[0];
    const float* W_in   = (const float*)d_in[1];
    const float* conv_w = (const float*)d_in[2];
    const float* conv_b = (const float*)d_in[3];
    const float* A      = (const float*)d_in[4];
    const float* Bp     = (const float*)d_in[5];
    const float* Cp     = (const float*)d_in[6];
    const float* W_out  = (const float*)d_in[8];
    float* out = (float*)d_out;

    char* ws = (char*)d_ws;
    float* xp    = (float*)ws;                       // [0,32M): scan input
    ushort* Whi  = (ushort*)(ws + (32u << 20));      // [32,40M)
    ushort* Wlo  = (ushort*)(ws + (40u << 20));      // [40,48M)
    ushort* yghi = Whi;                              // alias after GEMM1
    ushort* yglo = Wlo;
    ushort* Wohi = (ushort*)ws;                      // [0,4M)  (xp dead after scan)
    ushort* Wolo = (ushort*)(ws + (4u << 20));       // [4,8M)
    float*  Prest = (float*)(ws + (8u << 20));       // [8,32M): split-K partials 1..3
    // x hi/lo live in d_out (8 MB) — consumed by GEMM1, overwritten by GEMM2
    ushort* xhi = (ushort*)d_out;
    ushort* xlo = xhi + (size_t)MROWS * D_MODEL;

    dim3 blk(256);
    const int n1 = NPROJ * D_MODEL / 8;   // 524288
    const int n2 = MROWS * D_MODEL / 8;   // 262144
    splitbf2_k<<<dim3((n1 + n2) / 256), blk, 0, stream>>>(
        W_in, Whi, Wlo, n1, x, xhi, xlo, n2);
    gemm_pipe<NPROJ, D_MODEL, 1, false>
        <<<dim3(32, 16), blk, 0, stream>>>(xhi, xlo, Whi, Wlo, xp, nullptr);
    scan_kernel<<<dim3(BSZ * NCHK * (INNER / 256)), blk, 0, stream>>>(
        xp, conv_w, conv_b, A, Bp, Cp, yghi, yglo);
    splitbf_frag<INNER><<<dim3((D_MODEL * INNER / 8) / 256), blk, 0, stream>>>(
        W_out, Wohi, Wolo, D_MODEL * INNER / 8);
    gemm_pipe<D_MODEL, INNER, 4, true>
        <<<dim3(8, 16, 4), blk, 0, stream>>>(yghi, yglo, Wohi, Wolo, out, Prest);
    reduce_sk<<<dim3((MROWS * D_MODEL / 4) / 256), blk, 0, stream>>>(out, Prest);
}

// Round 16
// 124.145 us; speedup vs baseline: 1.3214x; 1.3214x over previous
//
#include <hip/hip_runtime.h>
#include <hip/hip_bf16.h>

#define D_MODEL 1024
#define INNER   2048
#define NPROJ   4096   // 2*INNER
#define BSZ     2
#define LSEQ    1024
#define MROWS   (BSZ*LSEQ)  // 2048

#define CHUNK 32
#define WARM  24
#define NCHK  (LSEQ / CHUNK)   // 32

using short8   = __attribute__((ext_vector_type(8))) short;
using ushort8  = __attribute__((ext_vector_type(8))) unsigned short;
using f32x4    = __attribute__((ext_vector_type(4))) float;
typedef unsigned short ushort;

#define MFMA16(A,B,Cv) __builtin_amdgcn_mfma_f32_16x16x32_bf16(A,B,Cv,0,0,0)

__device__ __forceinline__ ushort tobf(float x) {
    return (ushort)(__builtin_bit_cast(unsigned, x) >> 16);
}
__device__ __forceinline__ float frombf(ushort h) {
    return __builtin_bit_cast(float, ((unsigned)h) << 16);
}
__device__ __forceinline__ void glds16(const void* g, void* l) {
    __builtin_amdgcn_global_load_lds((const __attribute__((address_space(1))) void*)g,
                                     (__attribute__((address_space(3))) void*)l, 16, 0, 0);
}

// f32 row-major (R x K) -> bf16 hi/lo in 16x32 FRAGMENT-LINEAR subtiles:
// subtile (rt,kt) = 16 rows x 32 cols; lane l = (kchunk<<4)|row holds 8 elems.
template<int K>
__device__ __forceinline__ void split_chunk(const float* __restrict__ in,
                                            ushort* __restrict__ hi,
                                            ushort* __restrict__ lo, int c) {
    int l = c & 63, sub = c >> 6;
    constexpr int KT = K / 32;
    int kt = sub % KT, rt = sub / KT;
    const float* src = in + (size_t)(rt * 16 + (l & 15)) * K + kt * 32 + (l >> 4) * 8;
    ushort8 h, lw;
#pragma unroll
    for (int j = 0; j < 8; ++j) {
        float x = src[j];
        h[j]  = tobf(x);
        lw[j] = tobf(x - frombf(h[j]));
    }
    *reinterpret_cast<ushort8*>(&hi[(size_t)c * 8]) = h;
    *reinterpret_cast<ushort8*>(&lo[(size_t)c * 8]) = lw;
}

template<int K>
__global__ __launch_bounds__(256) void splitbf_frag(const float* __restrict__ in,
                                                    ushort* __restrict__ hi,
                                                    ushort* __restrict__ lo, int nchunks) {
    int c = blockIdx.x * 256 + threadIdx.x;
    if (c >= nchunks) return;
    split_chunk<K>(in, hi, lo, c);
}

// fused: split two K=1024 matrices (W_in and x) in one launch
__global__ __launch_bounds__(256) void splitbf2_k(
    const float* __restrict__ in1, ushort* __restrict__ hi1, ushort* __restrict__ lo1, int n1,
    const float* __restrict__ in2, ushort* __restrict__ hi2, ushort* __restrict__ lo2, int n2) {
    int c = blockIdx.x * 256 + threadIdx.x;
    if (c < n1) {
        split_chunk<D_MODEL>(in1, hi1, lo1, c);
    } else {
        int cc = c - n1;
        if (cc < n2) split_chunk<D_MODEL>(in2, hi2, lo2, cc);
    }
}

// ---------------------------------------------------------------------------
// Pipelined bf16x3 GEMM (16x16x32): C[MROWS,NCOL] = A[MROWS,K]*B[NCOL,K]^T.
// BM=128 fixed; BN=256 -> 8 waves (2Mx4N), NBUF=3, counted vmcnt(6) (R10);
// BN=128 -> 4 waves (2Mx2N), NBUF=2, vmcnt(0) drain but 64KB LDS -> 2 WGs/CU
// so the drain hides under the co-resident WG's MFMA.
// Per K-tile: R1{MFMA hh; read bl; issue Bh} R2{MFMA hl; read al; issue Bl}
// BAR1 R3{MFMA lh; issue A; vmcnt} BAR2 R4{read next ah,bh}.
// ---------------------------------------------------------------------------
template<int BN, int NCOL, int K, int SPLITK, bool PARTIAL, int NBUF, int NTHR>
__global__ __launch_bounds__(NTHR, 1) void gemm_pipe(
    const ushort* __restrict__ Agh, const ushort* __restrict__ Agl,
    const ushort* __restrict__ Bgh, const ushort* __restrict__ Bgl,
    float* __restrict__ C0, float* __restrict__ Crest)
{
    constexpr int BM = 128;
    constexpr int NW = NTHR / 64;
    constexpr int KT = K / 32;
    constexpr int NT = KT / SPLITK;
    constexpr int CB = (BN / 16) / NW;   // B subtile-loads per wave per matrix
    constexpr int CA = (BM / 16) / NW;   // A subtile-loads per wave per matrix
    __shared__ ushort Ah[NBUF][BM * 32], Al[NBUF][BM * 32];
    __shared__ ushort Bh[NBUF][BN * 32], Bl[NBUF][BN * 32];

    const int tid = threadIdx.x;
    const int wid = tid >> 6, lane = tid & 63;
    const int lm = lane & 15, lk = lane >> 4;

    constexpr int NTX = NCOL / BN;
    constexpr int NXY = NTX * (MROWS / BM);
    constexpr int CPX = NXY / 8;
    int lin = blockIdx.y * NTX + blockIdx.x;
    int swz = (lin & 7) * CPX + (lin >> 3);
    const int m0 = (swz / NTX) * BM, n0 = (swz % NTX) * BN;
    const int t0 = (SPLITK > 1 ? blockIdx.z : 0) * NT;
    const int wm = (NW == 8) ? (wid >> 2) * 64 : (wid >> 1) * 64;
    const int wn = (NW == 8) ? (wid & 3) * 64 : (wid & 1) * 64;

    f32x4 acc[4][4] = {};

    auto issueB = [&](const ushort* __restrict__ src, ushort* dst, int tg) {
#pragma unroll
        for (int ci = 0; ci < CB; ++ci) {
            int s = wid + ci * NW;
            const ushort* g = src + ((size_t)((n0 >> 4) + s) * KT + tg) * 512 + lane * 8;
            glds16(g, dst + s * 512);
        }
    };
    auto issueA = [&](const ushort* __restrict__ src, ushort* dst, int tg) {
#pragma unroll
        for (int ci = 0; ci < CA; ++ci) {
            int s = wid + ci * NW;
            const ushort* g = src + ((size_t)((m0 >> 4) + s) * KT + tg) * 512 + lane * 8;
            glds16(g, dst + s * 512);
        }
    };
    auto stageTile = [&](int t, int b) {
        issueB(Bgh, &Bh[b][0], t0 + t);
        issueB(Bgl, &Bl[b][0], t0 + t);
        issueA(Agh, &Ah[b][0], t0 + t);
        issueA(Agl, &Al[b][0], t0 + t);
    };

    // prologue
    if constexpr (NBUF == 3) {
        stageTile(0, 0);
        stageTile(1, 1);
        asm volatile("s_waitcnt vmcnt(6)" ::: "memory");   // tile 0 landed
    } else {
        stageTile(0, 0);
        asm volatile("s_waitcnt vmcnt(0)" ::: "memory");
    }
    __builtin_amdgcn_s_barrier();

    short8 ah[4], bh[4];
#pragma unroll
    for (int i = 0; i < 4; ++i)
        ah[i] = *reinterpret_cast<const short8*>(&Ah[0][((wm >> 4) + i) * 512 + lane * 8]);
#pragma unroll
    for (int q = 0; q < 4; ++q)
        bh[q] = *reinterpret_cast<const short8*>(&Bh[0][((wn >> 4) + q) * 512 + lane * 8]);

    int cur = 0;
    for (int t = 0; t < NT; ++t) {
        int nxt, stg;
        bool pf;
        if constexpr (NBUF == 3) {
            nxt = cur + 1; if (nxt == 3) nxt = 0;
            stg = cur + 2; if (stg >= 3) stg -= 3;
            pf = (t + 2 < NT);
        } else {
            nxt = cur ^ 1;
            stg = nxt;
            pf = (t + 1 < NT);
        }
        const int tpre = (NBUF == 3) ? t + 2 : t + 1;
        short8 bl[4], al[4];

        // ---- R1: hh MFMA; read bl(cur); issue Bh prefetch ----
        asm volatile("s_waitcnt lgkmcnt(0)" ::: "memory");
        __builtin_amdgcn_sched_barrier(0);
        __builtin_amdgcn_s_setprio(1);
#pragma unroll
        for (int i = 0; i < 4; ++i)
#pragma unroll
            for (int q = 0; q < 4; ++q)
                acc[i][q] = MFMA16(ah[i], bh[q], acc[i][q]);
        __builtin_amdgcn_s_setprio(0);
#pragma unroll
        for (int q = 0; q < 4; ++q)
            bl[q] = *reinterpret_cast<const short8*>(&Bl[cur][((wn >> 4) + q) * 512 + lane * 8]);
        if (pf) issueB(Bgh, &Bh[stg][0], t0 + tpre);

        // ---- R2: hl MFMA; read al(cur); issue Bl prefetch ----
        asm volatile("s_waitcnt lgkmcnt(0)" ::: "memory");
        __builtin_amdgcn_sched_barrier(0);
        __builtin_amdgcn_s_setprio(1);
#pragma unroll
        for (int i = 0; i < 4; ++i)
#pragma unroll
            for (int q = 0; q < 4; ++q)
                acc[i][q] = MFMA16(ah[i], bl[q], acc[i][q]);
        __builtin_amdgcn_s_setprio(0);
#pragma unroll
        for (int i = 0; i < 4; ++i)
            al[i] = *reinterpret_cast<const short8*>(&Al[cur][((wm >> 4) + i) * 512 + lane * 8]);
        if (pf) issueB(Bgl, &Bl[stg][0], t0 + tpre);
        __builtin_amdgcn_s_barrier();   // BAR1

        // ---- R3: lh MFMA; issue A prefetch; counted vmcnt ----
        asm volatile("s_waitcnt lgkmcnt(0)" ::: "memory");
        __builtin_amdgcn_sched_barrier(0);
        __builtin_amdgcn_s_setprio(1);
#pragma unroll
        for (int i = 0; i < 4; ++i)
#pragma unroll
            for (int q = 0; q < 4; ++q)
                acc[i][q] = MFMA16(al[i], bh[q], acc[i][q]);
        __builtin_amdgcn_s_setprio(0);
        if (pf) {
            issueA(Agh, &Ah[stg][0], t0 + tpre);
            issueA(Agl, &Al[stg][0], t0 + tpre);
        }
        if (NBUF == 3 && pf) asm volatile("s_waitcnt vmcnt(6)" ::: "memory");
        else                 asm volatile("s_waitcnt vmcnt(0)" ::: "memory");
        __builtin_amdgcn_s_barrier();   // BAR2: next tile fully staged

        // ---- R4: read next tile's hh frags ----
        if (t + 1 < NT) {
#pragma unroll
            for (int i = 0; i < 4; ++i)
                ah[i] = *reinterpret_cast<const short8*>(&Ah[nxt][((wm >> 4) + i) * 512 + lane * 8]);
#pragma unroll
            for (int q = 0; q < 4; ++q)
                bh[q] = *reinterpret_cast<const short8*>(&Bh[nxt][((wn >> 4) + q) * 512 + lane * 8]);
        }
        cur = nxt;
    }

    float* C = C0;
    if constexpr (PARTIAL) {
        int kz = blockIdx.z;
        if (kz != 0) C = Crest + (size_t)(kz - 1) * MROWS * NCOL;
    }
#pragma unroll
    for (int i = 0; i < 4; ++i)
#pragma unroll
        for (int j = 0; j < 4; ++j)
#pragma unroll
            for (int r = 0; r < 4; ++r) {
                int row = m0 + wm + i * 16 + lk * 4 + r;
                int col = n0 + wn + j * 16 + lm;
                C[(size_t)row * NCOL + col] = acc[i][j][r];
            }
}

// out += sum of 3 partials (out already holds partial 0)
__global__ __launch_bounds__(256) void reduce_sk(float* __restrict__ out,
                                                 const float* __restrict__ rest) {
    constexpr size_t MN = (size_t)MROWS * D_MODEL;
    size_t i = ((size_t)blockIdx.x * 256 + threadIdx.x) * 4;
    f32x4 a = *reinterpret_cast<const f32x4*>(&out[i]);
    f32x4 b = *reinterpret_cast<const f32x4*>(&rest[i]);
    f32x4 c = *reinterpret_cast<const f32x4*>(&rest[MN + i]);
    f32x4 d = *reinterpret_cast<const f32x4*>(&rest[2 * MN + i]);
    *reinterpret_cast<f32x4*>(&out[i]) = (a + b) + (c + d);
}

// Chunk-parallel fused conv + sigmoid + scan + gate; emits yg as bf16 hi/lo
// in 16x32 fragment-linear order for GEMM2's A (K = INNER = 2048, KT = 64).
__global__ __launch_bounds__(256) void scan_kernel(
    const float* __restrict__ xp,
    const float* __restrict__ conv_w, const float* __restrict__ conv_b,
    const float* __restrict__ Aa, const float* __restrict__ Bp, const float* __restrict__ Cp,
    ushort* __restrict__ yhi, ushort* __restrict__ ylo)
{
    const int NB = INNER / 256;  // 8
    int tid = threadIdx.x;
    int bi = blockIdx.x;
    int b  = bi / (NCHK * NB);
    int r  = bi % (NCHK * NB);
    int ch = r / NB;
    int n  = (r % NB) * 256 + tid;

    float4 w = *reinterpret_cast<const float4*>(&conv_w[n * 4]);
    float cb = conv_b[n];
    float An[16], Bn[16], Cn[16], st[16];
#pragma unroll
    for (int i = 0; i < 16; i += 4) {
        float4 va = *reinterpret_cast<const float4*>(&Aa[n * 16 + i]);
        float4 vb = *reinterpret_cast<const float4*>(&Bp[n * 16 + i]);
        float4 vc = *reinterpret_cast<const float4*>(&Cp[n * 16 + i]);
        An[i]=va.x; An[i+1]=va.y; An[i+2]=va.z; An[i+3]=va.w;
        Bn[i]=vb.x; Bn[i+1]=vb.y; Bn[i+2]=vb.z; Bn[i+3]=vb.w;
        Cn[i]=vc.x; Cn[i+1]=vc.y; Cn[i+2]=vc.z; Cn[i+3]=vc.w;
    }
#pragma unroll
    for (int s = 0; s < 16; ++s) st[s] = 0.f;

    int out0 = ch * CHUNK;
    int lstart = (out0 >= WARM) ? (out0 - WARM) : 0;
    float u0 = 0.f, u1 = 0.f, u2 = 0.f;
    const float* xb = xp + (size_t)b * LSEQ * NPROJ;
    size_t fcol = (size_t)(n >> 5) * 512 + ((n >> 3) & 3) * 128 + (n & 7);

    for (int l = lstart; l < out0; l += 8) {
        float uv[8];
#pragma unroll
        for (int i = 0; i < 8; ++i)
            uv[i] = xb[(size_t)(l + i) * NPROJ + 2 * n];
#pragma unroll
        for (int i = 0; i < 8; ++i) {
            float ul = uv[i];
            float xc = cb + w.x * u0 + w.y * u1 + w.z * u2 + w.w * ul;
            u0 = u1; u1 = u2; u2 = ul;
            float d = 1.f / (1.f + __expf(-xc));
            float dxc = d * xc;
#pragma unroll
            for (int s = 0; s < 16; ++s)
                st[s] = (An[s] * d) * st[s] + Bn[s] * dxc;
        }
    }
    for (int lt = 0; lt < CHUNK; lt += 8) {
        float uv[8], gv[8];
#pragma unroll
        for (int i = 0; i < 8; ++i) {
            float2 ug = *reinterpret_cast<const float2*>(
                &xb[(size_t)(out0 + lt + i) * NPROJ + 2 * n]);
            uv[i] = ug.x; gv[i] = ug.y;
        }
#pragma unroll
        for (int i = 0; i < 8; ++i) {
            float ul = uv[i];
            float xc = cb + w.x * u0 + w.y * u1 + w.z * u2 + w.w * ul;
            u0 = u1; u1 = u2; u2 = ul;
            float d = 1.f / (1.f + __expf(-xc));
            float dxc = d * xc;
            float y0 = 0.f, y1 = 0.f, y2 = 0.f, y3 = 0.f;
#pragma unroll
            for (int s = 0; s < 16; s += 4) {
                st[s + 0] = (An[s + 0] * d) * st[s + 0] + Bn[s + 0] * dxc;
                st[s + 1] = (An[s + 1] * d) * st[s + 1] + Bn[s + 1] * dxc;
                st[s + 2] = (An[s + 2] * d) * st[s + 2] + Bn[s + 2] * dxc;
                st[s + 3] = (An[s + 3] * d) * st[s + 3] + Bn[s + 3] * dxc;
                y0 += st[s + 0] * Cn[s + 0];
                y1 += st[s + 1] * Cn[s + 1];
                y2 += st[s + 2] * Cn[s + 2];
                y3 += st[s + 3] * Cn[s + 3];
            }
            float y = (y0 + y1) + (y2 + y3);
            float g = 1.f / (1.f + __expf(-gv[i]));
            float o = y * g;
            int R = b * LSEQ + out0 + lt + i;
            size_t fi = ((size_t)(R >> 4) * 64) * 512 + fcol + (R & 15) * 8;
            ushort hh = tobf(o);
            yhi[fi] = hh;
            ylo[fi] = tobf(o - frombf(hh));
        }
    }
}

extern "C" void kernel_launch(void* const* d_in, const int* in_sizes, int n_in,
                              void* d_out, int out_size, void* d_ws, size_t ws_size,
                              hipStream_t stream) {
    const float* x      = (const float*)d_in[0];
    const float* W_in   = (const float*)d_in[1];
    const float* conv_w = (const float*)d_in[2];
    const float* conv_b = (const float*)d_in[3];
    const float* A      = (const float*)d_in[4];
    const float* Bp     = (const float*)d_in[5];
    const float* Cp     = (const float*)d_in[6];
    const float* W_out  = (const float*)d_in[8];
    float* out = (float*)d_out;

    char* ws = (char*)d_ws;
    float* xp    = (float*)ws;                       // [0,32M): scan input
    ushort* Whi  = (ushort*)(ws + (32u << 20));      // [32,40M)
    ushort* Wlo  = (ushort*)(ws + (40u << 20));      // [40,48M)
    ushort* yghi = Whi;                              // alias after GEMM1
    ushort* yglo = Wlo;
    ushort* Wohi = (ushort*)ws;                      // [0,4M)  (xp dead after scan)
    ushort* Wolo = (ushort*)(ws + (4u << 20));       // [4,8M)
    float*  Prest = (float*)(ws + (8u << 20));       // [8,32M): split-K partials 1..3
    // x hi/lo live in d_out (8 MB) — consumed by GEMM1, overwritten by GEMM2
    ushort* xhi = (ushort*)d_out;
    ushort* xlo = xhi + (size_t)MROWS * D_MODEL;

    dim3 blk(256);
    const int n1 = NPROJ * D_MODEL / 8;   // 524288
    const int n2 = MROWS * D_MODEL / 8;   // 262144
    splitbf2_k<<<dim3((n1 + n2) / 256), blk, 0, stream>>>(
        W_in, Whi, Wlo, n1, x, xhi, xlo, n2);
    gemm_pipe<256, NPROJ, D_MODEL, 1, false, 3, 512>
        <<<dim3(16, 16), dim3(512), 0, stream>>>(xhi, xlo, Whi, Wlo, xp, nullptr);
    scan_kernel<<<dim3(BSZ * NCHK * (INNER / 256)), blk, 0, stream>>>(
        xp, conv_w, conv_b, A, Bp, Cp, yghi, yglo);
    splitbf_frag<INNER><<<dim3((D_MODEL * INNER / 8) / 256), blk, 0, stream>>>(
        W_out, Wohi, Wolo, D_MODEL * INNER / 8);
    gemm_pipe<128, D_MODEL, INNER, 4, true, 2, 256>
        <<<dim3(8, 16, 4), dim3(256), 0, stream>>>(yghi, yglo, Wohi, Wolo, out, Prest);
    reduce_sk<<<dim3((MROWS * D_MODEL / 4) / 256), blk, 0, stream>>>(out, Prest);
}

// Round 17
// 104.671 us; speedup vs baseline: 1.5672x; 1.1861x over previous
//
#include <hip/hip_runtime.h>
#include <hip/hip_bf16.h>

#define D_MODEL 1024
#define INNER   2048
#define NPROJ   4096   // 2*INNER
#define BSZ     2
#define LSEQ    1024
#define MROWS   (BSZ*LSEQ)  // 2048

#define CHUNK 32
#define WARM  24
#define NCHK  (LSEQ / CHUNK)   // 32

using short8   = __attribute__((ext_vector_type(8))) short;
using ushort8  = __attribute__((ext_vector_type(8))) unsigned short;
using f32x4    = __attribute__((ext_vector_type(4))) float;
using i32x4    = __attribute__((ext_vector_type(4))) int;
using char16v  = __attribute__((ext_vector_type(16))) char;
typedef unsigned short ushort;
typedef unsigned char uchar;

#define MFMA16(A,B,Cv) __builtin_amdgcn_mfma_f32_16x16x32_bf16(A,B,Cv,0,0,0)
#define MFMAI8(A,B,Cv) __builtin_amdgcn_mfma_i32_16x16x64_i8(A,B,Cv,0,0,0)

__device__ __forceinline__ ushort tobf(float x) {
    return (ushort)(__builtin_bit_cast(unsigned, x) >> 16);
}
__device__ __forceinline__ float frombf(ushort h) {
    return __builtin_bit_cast(float, ((unsigned)h) << 16);
}
__device__ __forceinline__ void glds16(const void* g, void* l) {
    __builtin_amdgcn_global_load_lds((const __attribute__((address_space(1))) void*)g,
                                     (__attribute__((address_space(3))) void*)l, 16, 0, 0);
}

// ---------------------------------------------------------------------------
// Row-wise two-digit i8 quantization into 16x64 FRAGMENT-LINEAR subtiles.
// x ~ s*(h + l/256), s = rowmax/127. Subtile (rt,kt) = 16 rows x 64 k;
// lane ll = (kchunk<<4)|row holds 16 contiguous k-bytes.
// One wave per row; rows [0,RW) -> W arrays, rows [RW,..) -> X arrays.
// ---------------------------------------------------------------------------
__global__ __launch_bounds__(256) void quant_rows(
    const float* __restrict__ W, uchar* __restrict__ Wh, uchar* __restrict__ Wl,
    float* __restrict__ sW, int RW,
    const float* __restrict__ X, uchar* __restrict__ Xh, uchar* __restrict__ Xl,
    float* __restrict__ sX)
{
    const int K = 1024, KT64 = K / 64;
    int gw = blockIdx.x * 4 + (threadIdx.x >> 6);
    int lane = threadIdx.x & 63;
    const float* src; uchar *dh, *dl; float* ss; int r;
    if (gw < RW) { r = gw;      src = W + (size_t)r * K; dh = Wh; dl = Wl; ss = sW; }
    else         { r = gw - RW; src = X + (size_t)r * K; dh = Xh; dl = Xl; ss = sX; }

    float v[16];
#pragma unroll
    for (int p = 0; p < 4; ++p) {
        float4 f = *reinterpret_cast<const float4*>(src + lane * 16 + p * 4);
        v[p*4+0] = f.x; v[p*4+1] = f.y; v[p*4+2] = f.z; v[p*4+3] = f.w;
    }
    float mx = 0.f;
#pragma unroll
    for (int j = 0; j < 16; ++j) mx = fmaxf(mx, fabsf(v[j]));
#pragma unroll
    for (int off = 1; off < 64; off <<= 1) mx = fmaxf(mx, __shfl_xor(mx, off));
    float s1 = fmaxf(mx, 1e-20f) / 127.f;
    if (lane == 0) ss[r] = s1;
    float inv = 1.f / s1;
    char16v hb, lb;
#pragma unroll
    for (int j = 0; j < 16; ++j) {
        float t = v[j] * inv;                       // in [-127, 127]
        float h = rintf(t);
        float l = rintf((t - h) * 256.f);
        l = fminf(fmaxf(l, -128.f), 127.f);
        hb[j] = (char)(int)h;
        lb[j] = (char)(int)l;
    }
    size_t byte = (((size_t)(r >> 4) * KT64 + (lane >> 2)) * 64
                   + ((lane & 3) << 4) + (r & 15)) * 16;
    *reinterpret_cast<i32x4*>(dh + byte) = *reinterpret_cast<const i32x4*>(&hb);
    *reinterpret_cast<i32x4*>(dl + byte) = *reinterpret_cast<const i32x4*>(&lb);
}

// ---------------------------------------------------------------------------
// GEMM1 (in_proj) in i8x3: C[2048,4096] = x * W_in^T.
// xp[r,c] = sX[r]*sW[c]*(acc_hh + (acc_hl+acc_lh)/256), i32 accumulators.
// 512 thr / 8 waves (2Mx4N, wave 64x64), BM=128 BN=256 BK=64, NT=16,
// NBUF=3 (48KB/buf, 144KB), 6 glds/thread/tile, counted vmcnt(6).
// Same R1/R2/R3/R4 pipeline as the proven bf16 kernel.
// ---------------------------------------------------------------------------
__global__ __launch_bounds__(512, 1) void gemm1_i8(
    const uchar* __restrict__ Xh, const uchar* __restrict__ Xl, const float* __restrict__ sX,
    const uchar* __restrict__ Wh, const uchar* __restrict__ Wl, const float* __restrict__ sW,
    float* __restrict__ C)
{
    constexpr int KT64 = D_MODEL / 64;   // 16
    constexpr int NT = 16;
    __shared__ uchar Ah[3][8192], Al[3][8192];     // 128x64 i8 per buf (8 subtiles)
    __shared__ uchar Bh[3][16384], Bl[3][16384];   // 256x64 i8 per buf (16 subtiles)

    const int tid = threadIdx.x;
    const int wid = tid >> 6, lane = tid & 63;
    const int lm = lane & 15, lk = lane >> 4;

    constexpr int NTX = NPROJ / 256;     // 16
    constexpr int CPX = (NTX * (MROWS / 128)) / 8;
    int lin = blockIdx.y * NTX + blockIdx.x;
    int swz = (lin & 7) * CPX + (lin >> 3);
    const int m0 = (swz / NTX) * 128, n0 = (swz % NTX) * 256;
    const int wm = (wid >> 2) * 64, wn = (wid & 3) * 64;

    i32x4 acc1[4][4] = {};   // hh
    i32x4 acc2[4][4] = {};   // hl + lh (scale /256)

    auto issueB = [&](const uchar* __restrict__ src, uchar* dst, int t, int ci) {
        int s = wid + ci * 8;
        const uchar* g = src + ((size_t)((n0 >> 4) + s) * KT64 + t) * 1024 + lane * 16;
        glds16(g, dst + s * 1024);
    };
    auto issueA = [&](const uchar* __restrict__ src, uchar* dst, int t) {
        const uchar* g = src + ((size_t)((m0 >> 4) + wid) * KT64 + t) * 1024 + lane * 16;
        glds16(g, dst + wid * 1024);
    };
    auto stageTile = [&](int t, int b) {
        issueB(Wh, &Bh[b][0], t, 0); issueB(Wh, &Bh[b][0], t, 1);
        issueB(Wl, &Bl[b][0], t, 0); issueB(Wl, &Bl[b][0], t, 1);
        issueA(Xh, &Ah[b][0], t);    issueA(Xl, &Al[b][0], t);
    };

    stageTile(0, 0);
    stageTile(1, 1);
    asm volatile("s_waitcnt vmcnt(6)" ::: "memory");
    __builtin_amdgcn_s_barrier();

    i32x4 ah[4], bh[4];
#pragma unroll
    for (int i = 0; i < 4; ++i)
        ah[i] = *reinterpret_cast<const i32x4*>(&Ah[0][((wm >> 4) + i) * 1024 + lane * 16]);
#pragma unroll
    for (int q = 0; q < 4; ++q)
        bh[q] = *reinterpret_cast<const i32x4*>(&Bh[0][((wn >> 4) + q) * 1024 + lane * 16]);

    int cur = 0;
    for (int t = 0; t < NT; ++t) {
        int nxt = cur + 1; if (nxt == 3) nxt = 0;
        int stg = cur + 2; if (stg >= 3) stg -= 3;
        const bool pf = (t + 2 < NT);
        i32x4 bl[4], al[4];

        // ---- R1: hh MFMA -> acc1; read bl(cur); issue Bh(t+2) ----
        asm volatile("s_waitcnt lgkmcnt(0)" ::: "memory");
        __builtin_amdgcn_sched_barrier(0);
        __builtin_amdgcn_s_setprio(1);
#pragma unroll
        for (int i = 0; i < 4; ++i)
#pragma unroll
            for (int q = 0; q < 4; ++q)
                acc1[i][q] = MFMAI8(ah[i], bh[q], acc1[i][q]);
        __builtin_amdgcn_s_setprio(0);
#pragma unroll
        for (int q = 0; q < 4; ++q)
            bl[q] = *reinterpret_cast<const i32x4*>(&Bl[cur][((wn >> 4) + q) * 1024 + lane * 16]);
        if (pf) {
            issueB(Wh, &Bh[stg][0], t + 2, 0);
            issueB(Wh, &Bh[stg][0], t + 2, 1);
        }

        // ---- R2: hl MFMA -> acc2; read al(cur); issue Bl(t+2) ----
        asm volatile("s_waitcnt lgkmcnt(0)" ::: "memory");
        __builtin_amdgcn_sched_barrier(0);
        __builtin_amdgcn_s_setprio(1);
#pragma unroll
        for (int i = 0; i < 4; ++i)
#pragma unroll
            for (int q = 0; q < 4; ++q)
                acc2[i][q] = MFMAI8(ah[i], bl[q], acc2[i][q]);
        __builtin_amdgcn_s_setprio(0);
#pragma unroll
        for (int i = 0; i < 4; ++i)
            al[i] = *reinterpret_cast<const i32x4*>(&Al[cur][((wm >> 4) + i) * 1024 + lane * 16]);
        if (pf) {
            issueB(Wl, &Bl[stg][0], t + 2, 0);
            issueB(Wl, &Bl[stg][0], t + 2, 1);
        }
        __builtin_amdgcn_s_barrier();   // BAR1

        // ---- R3: lh MFMA -> acc2; issue A(t+2); counted vmcnt ----
        asm volatile("s_waitcnt lgkmcnt(0)" ::: "memory");
        __builtin_amdgcn_sched_barrier(0);
        __builtin_amdgcn_s_setprio(1);
#pragma unroll
        for (int i = 0; i < 4; ++i)
#pragma unroll
            for (int q = 0; q < 4; ++q)
                acc2[i][q] = MFMAI8(al[i], bh[q], acc2[i][q]);
        __builtin_amdgcn_s_setprio(0);
        if (pf) {
            issueA(Xh, &Ah[stg][0], t + 2);
            issueA(Xl, &Al[stg][0], t + 2);
        }
        if (pf) asm volatile("s_waitcnt vmcnt(6)" ::: "memory");
        else    asm volatile("s_waitcnt vmcnt(0)" ::: "memory");
        __builtin_amdgcn_s_barrier();   // BAR2

        // ---- R4: read next tile's hh frags ----
        if (t + 1 < NT) {
#pragma unroll
            for (int i = 0; i < 4; ++i)
                ah[i] = *reinterpret_cast<const i32x4*>(&Ah[nxt][((wm >> 4) + i) * 1024 + lane * 16]);
#pragma unroll
            for (int q = 0; q < 4; ++q)
                bh[q] = *reinterpret_cast<const i32x4*>(&Bh[nxt][((wn >> 4) + q) * 1024 + lane * 16]);
        }
        cur = nxt;
    }

    // epilogue: dequantize. C/D layout: col=lane&15, row=(lane>>4)*4+r
#pragma unroll
    for (int i = 0; i < 4; ++i) {
        int r0 = m0 + wm + i * 16 + lk * 4;
        float4 s4 = *reinterpret_cast<const float4*>(&sX[r0]);
        float sa[4] = {s4.x, s4.y, s4.z, s4.w};
#pragma unroll
        for (int j = 0; j < 4; ++j) {
            int col = n0 + wn + j * 16 + lm;
            float sb = sW[col];
#pragma unroll
            for (int r = 0; r < 4; ++r) {
                float o = sa[r] * sb *
                    ((float)acc1[i][j][r] + (float)acc2[i][j][r] * 0.00390625f);
                C[(size_t)(r0 + r) * NPROJ + col] = o;
            }
        }
    }
}

// f32 row-major (R x K) -> bf16 hi/lo in 16x32 FRAGMENT-LINEAR subtiles (GEMM2).
template<int K>
__device__ __forceinline__ void split_chunk(const float* __restrict__ in,
                                            ushort* __restrict__ hi,
                                            ushort* __restrict__ lo, int c) {
    int l = c & 63, sub = c >> 6;
    constexpr int KT = K / 32;
    int kt = sub % KT, rt = sub / KT;
    const float* src = in + (size_t)(rt * 16 + (l & 15)) * K + kt * 32 + (l >> 4) * 8;
    ushort8 h, lw;
#pragma unroll
    for (int j = 0; j < 8; ++j) {
        float x = src[j];
        h[j]  = tobf(x);
        lw[j] = tobf(x - frombf(h[j]));
    }
    *reinterpret_cast<ushort8*>(&hi[(size_t)c * 8]) = h;
    *reinterpret_cast<ushort8*>(&lo[(size_t)c * 8]) = lw;
}

template<int K>
__global__ __launch_bounds__(256) void splitbf_frag(const float* __restrict__ in,
                                                    ushort* __restrict__ hi,
                                                    ushort* __restrict__ lo, int nchunks) {
    int c = blockIdx.x * 256 + threadIdx.x;
    if (c >= nchunks) return;
    split_chunk<K>(in, hi, lo, c);
}

// ---------------------------------------------------------------------------
// GEMM2 (out_proj): bf16x3 pipelined, 128x128, 4 waves, NBUF=2, 64KB LDS ->
// 2 WGs/CU; split-K=4 + reduce. (Proven R13 config.)
// ---------------------------------------------------------------------------
template<int BN, int NCOL, int K, int SPLITK, bool PARTIAL, int NBUF, int NTHR>
__global__ __launch_bounds__(NTHR, 1) void gemm_pipe(
    const ushort* __restrict__ Agh, const ushort* __restrict__ Agl,
    const ushort* __restrict__ Bgh, const ushort* __restrict__ Bgl,
    float* __restrict__ C0, float* __restrict__ Crest)
{
    constexpr int BM = 128;
    constexpr int NW = NTHR / 64;
    constexpr int KT = K / 32;
    constexpr int NT = KT / SPLITK;
    constexpr int CB = (BN / 16) / NW;
    constexpr int CA = (BM / 16) / NW;
    __shared__ ushort Ah[NBUF][BM * 32], Al[NBUF][BM * 32];
    __shared__ ushort Bh[NBUF][BN * 32], Bl[NBUF][BN * 32];

    const int tid = threadIdx.x;
    const int wid = tid >> 6, lane = tid & 63;
    const int lm = lane & 15, lk = lane >> 4;

    constexpr int NTX = NCOL / BN;
    constexpr int NXY = NTX * (MROWS / BM);
    constexpr int CPX = NXY / 8;
    int lin = blockIdx.y * NTX + blockIdx.x;
    int swz = (lin & 7) * CPX + (lin >> 3);
    const int m0 = (swz / NTX) * BM, n0 = (swz % NTX) * BN;
    const int t0 = (SPLITK > 1 ? blockIdx.z : 0) * NT;
    const int wm = (NW == 8) ? (wid >> 2) * 64 : (wid >> 1) * 64;
    const int wn = (NW == 8) ? (wid & 3) * 64 : (wid & 1) * 64;

    f32x4 acc[4][4] = {};

    auto issueB = [&](const ushort* __restrict__ src, ushort* dst, int tg) {
#pragma unroll
        for (int ci = 0; ci < CB; ++ci) {
            int s = wid + ci * NW;
            const ushort* g = src + ((size_t)((n0 >> 4) + s) * KT + tg) * 512 + lane * 8;
            glds16(g, dst + s * 512);
        }
    };
    auto issueA = [&](const ushort* __restrict__ src, ushort* dst, int tg) {
#pragma unroll
        for (int ci = 0; ci < CA; ++ci) {
            int s = wid + ci * NW;
            const ushort* g = src + ((size_t)((m0 >> 4) + s) * KT + tg) * 512 + lane * 8;
            glds16(g, dst + s * 512);
        }
    };
    auto stageTile = [&](int t, int b) {
        issueB(Bgh, &Bh[b][0], t0 + t);
        issueB(Bgl, &Bl[b][0], t0 + t);
        issueA(Agh, &Ah[b][0], t0 + t);
        issueA(Agl, &Al[b][0], t0 + t);
    };

    if constexpr (NBUF == 3) {
        stageTile(0, 0);
        stageTile(1, 1);
        asm volatile("s_waitcnt vmcnt(6)" ::: "memory");
    } else {
        stageTile(0, 0);
        asm volatile("s_waitcnt vmcnt(0)" ::: "memory");
    }
    __builtin_amdgcn_s_barrier();

    short8 ah[4], bh[4];
#pragma unroll
    for (int i = 0; i < 4; ++i)
        ah[i] = *reinterpret_cast<const short8*>(&Ah[0][((wm >> 4) + i) * 512 + lane * 8]);
#pragma unroll
    for (int q = 0; q < 4; ++q)
        bh[q] = *reinterpret_cast<const short8*>(&Bh[0][((wn >> 4) + q) * 512 + lane * 8]);

    int cur = 0;
    for (int t = 0; t < NT; ++t) {
        int nxt, stg;
        bool pf;
        if constexpr (NBUF == 3) {
            nxt = cur + 1; if (nxt == 3) nxt = 0;
            stg = cur + 2; if (stg >= 3) stg -= 3;
            pf = (t + 2 < NT);
        } else {
            nxt = cur ^ 1;
            stg = nxt;
            pf = (t + 1 < NT);
        }
        const int tpre = (NBUF == 3) ? t + 2 : t + 1;
        short8 bl[4], al[4];

        asm volatile("s_waitcnt lgkmcnt(0)" ::: "memory");
        __builtin_amdgcn_sched_barrier(0);
        __builtin_amdgcn_s_setprio(1);
#pragma unroll
        for (int i = 0; i < 4; ++i)
#pragma unroll
            for (int q = 0; q < 4; ++q)
                acc[i][q] = MFMA16(ah[i], bh[q], acc[i][q]);
        __builtin_amdgcn_s_setprio(0);
#pragma unroll
        for (int q = 0; q < 4; ++q)
            bl[q] = *reinterpret_cast<const short8*>(&Bl[cur][((wn >> 4) + q) * 512 + lane * 8]);
        if (pf) issueB(Bgh, &Bh[stg][0], t0 + tpre);

        asm volatile("s_waitcnt lgkmcnt(0)" ::: "memory");
        __builtin_amdgcn_sched_barrier(0);
        __builtin_amdgcn_s_setprio(1);
#pragma unroll
        for (int i = 0; i < 4; ++i)
#pragma unroll
            for (int q = 0; q < 4; ++q)
                acc[i][q] = MFMA16(ah[i], bl[q], acc[i][q]);
        __builtin_amdgcn_s_setprio(0);
#pragma unroll
        for (int i = 0; i < 4; ++i)
            al[i] = *reinterpret_cast<const short8*>(&Al[cur][((wm >> 4) + i) * 512 + lane * 8]);
        if (pf) issueB(Bgl, &Bl[stg][0], t0 + tpre);
        __builtin_amdgcn_s_barrier();

        asm volatile("s_waitcnt lgkmcnt(0)" ::: "memory");
        __builtin_amdgcn_sched_barrier(0);
        __builtin_amdgcn_s_setprio(1);
#pragma unroll
        for (int i = 0; i < 4; ++i)
#pragma unroll
            for (int q = 0; q < 4; ++q)
                acc[i][q] = MFMA16(al[i], bh[q], acc[i][q]);
        __builtin_amdgcn_s_setprio(0);
        if (pf) {
            issueA(Agh, &Ah[stg][0], t0 + tpre);
            issueA(Agl, &Al[stg][0], t0 + tpre);
        }
        if (NBUF == 3 && pf) asm volatile("s_waitcnt vmcnt(6)" ::: "memory");
        else                 asm volatile("s_waitcnt vmcnt(0)" ::: "memory");
        __builtin_amdgcn_s_barrier();

        if (t + 1 < NT) {
#pragma unroll
            for (int i = 0; i < 4; ++i)
                ah[i] = *reinterpret_cast<const short8*>(&Ah[nxt][((wm >> 4) + i) * 512 + lane * 8]);
#pragma unroll
            for (int q = 0; q < 4; ++q)
                bh[q] = *reinterpret_cast<const short8*>(&Bh[nxt][((wn >> 4) + q) * 512 + lane * 8]);
        }
        cur = nxt;
    }

    float* C = C0;
    if constexpr (PARTIAL) {
        int kz = blockIdx.z;
        if (kz != 0) C = Crest + (size_t)(kz - 1) * MROWS * NCOL;
    }
#pragma unroll
    for (int i = 0; i < 4; ++i)
#pragma unroll
        for (int j = 0; j < 4; ++j)
#pragma unroll
            for (int r = 0; r < 4; ++r) {
                int row = m0 + wm + i * 16 + lk * 4 + r;
                int col = n0 + wn + j * 16 + lm;
                C[(size_t)row * NCOL + col] = acc[i][j][r];
            }
}

// out += sum of 3 partials (out already holds partial 0)
__global__ __launch_bounds__(256) void reduce_sk(float* __restrict__ out,
                                                 const float* __restrict__ rest) {
    constexpr size_t MN = (size_t)MROWS * D_MODEL;
    size_t i = ((size_t)blockIdx.x * 256 + threadIdx.x) * 4;
    f32x4 a = *reinterpret_cast<const f32x4*>(&out[i]);
    f32x4 b = *reinterpret_cast<const f32x4*>(&rest[i]);
    f32x4 c = *reinterpret_cast<const f32x4*>(&rest[MN + i]);
    f32x4 d = *reinterpret_cast<const f32x4*>(&rest[2 * MN + i]);
    *reinterpret_cast<f32x4*>(&out[i]) = (a + b) + (c + d);
}

// Chunk-parallel fused conv + sigmoid + scan + gate; emits yg as bf16 hi/lo
// in 16x32 fragment-linear order for GEMM2's A (K = INNER = 2048, KT = 64).
__global__ __launch_bounds__(256) void scan_kernel(
    const float* __restrict__ xp,
    const float* __restrict__ conv_w, const float* __restrict__ conv_b,
    const float* __restrict__ Aa, const float* __restrict__ Bp, const float* __restrict__ Cp,
    ushort* __restrict__ yhi, ushort* __restrict__ ylo)
{
    const int NB = INNER / 256;  // 8
    int tid = threadIdx.x;
    int bi = blockIdx.x;
    int b  = bi / (NCHK * NB);
    int r  = bi % (NCHK * NB);
    int ch = r / NB;
    int n  = (r % NB) * 256 + tid;

    float4 w = *reinterpret_cast<const float4*>(&conv_w[n * 4]);
    float cb = conv_b[n];
    float An[16], Bn[16], Cn[16], st[16];
#pragma unroll
    for (int i = 0; i < 16; i += 4) {
        float4 va = *reinterpret_cast<const float4*>(&Aa[n * 16 + i]);
        float4 vb = *reinterpret_cast<const float4*>(&Bp[n * 16 + i]);
        float4 vc = *reinterpret_cast<const float4*>(&Cp[n * 16 + i]);
        An[i]=va.x; An[i+1]=va.y; An[i+2]=va.z; An[i+3]=va.w;
        Bn[i]=vb.x; Bn[i+1]=vb.y; Bn[i+2]=vb.z; Bn[i+3]=vb.w;
        Cn[i]=vc.x; Cn[i+1]=vc.y; Cn[i+2]=vc.z; Cn[i+3]=vc.w;
    }
#pragma unroll
    for (int s = 0; s < 16; ++s) st[s] = 0.f;

    int out0 = ch * CHUNK;
    int lstart = (out0 >= WARM) ? (out0 - WARM) : 0;
    float u0 = 0.f, u1 = 0.f, u2 = 0.f;
    const float* xb = xp + (size_t)b * LSEQ * NPROJ;
    size_t fcol = (size_t)(n >> 5) * 512 + ((n >> 3) & 3) * 128 + (n & 7);

    for (int l = lstart; l < out0; l += 8) {
        float uv[8];
#pragma unroll
        for (int i = 0; i < 8; ++i)
            uv[i] = xb[(size_t)(l + i) * NPROJ + 2 * n];
#pragma unroll
        for (int i = 0; i < 8; ++i) {
            float ul = uv[i];
            float xc = cb + w.x * u0 + w.y * u1 + w.z * u2 + w.w * ul;
            u0 = u1; u1 = u2; u2 = ul;
            float d = 1.f / (1.f + __expf(-xc));
            float dxc = d * xc;
#pragma unroll
            for (int s = 0; s < 16; ++s)
                st[s] = (An[s] * d) * st[s] + Bn[s] * dxc;
        }
    }
    for (int lt = 0; lt < CHUNK; lt += 8) {
        float uv[8], gv[8];
#pragma unroll
        for (int i = 0; i < 8; ++i) {
            float2 ug = *reinterpret_cast<const float2*>(
                &xb[(size_t)(out0 + lt + i) * NPROJ + 2 * n]);
            uv[i] = ug.x; gv[i] = ug.y;
        }
#pragma unroll
        for (int i = 0; i < 8; ++i) {
            float ul = uv[i];
            float xc = cb + w.x * u0 + w.y * u1 + w.z * u2 + w.w * ul;
            u0 = u1; u1 = u2; u2 = ul;
            float d = 1.f / (1.f + __expf(-xc));
            float dxc = d * xc;
            float y0 = 0.f, y1 = 0.f, y2 = 0.f, y3 = 0.f;
#pragma unroll
            for (int s = 0; s < 16; s += 4) {
                st[s + 0] = (An[s + 0] * d) * st[s + 0] + Bn[s + 0] * dxc;
                st[s + 1] = (An[s + 1] * d) * st[s + 1] + Bn[s + 1] * dxc;
                st[s + 2] = (An[s + 2] * d) * st[s + 2] + Bn[s + 2] * dxc;
                st[s + 3] = (An[s + 3] * d) * st[s + 3] + Bn[s + 3] * dxc;
                y0 += st[s + 0] * Cn[s + 0];
                y1 += st[s + 1] * Cn[s + 1];
                y2 += st[s + 2] * Cn[s + 2];
                y3 += st[s + 3] * Cn[s + 3];
            }
            float y = (y0 + y1) + (y2 + y3);
            float g = 1.f / (1.f + __expf(-gv[i]));
            float o = y * g;
            int R = b * LSEQ + out0 + lt + i;
            size_t fi = ((size_t)(R >> 4) * 64) * 512 + fcol + (R & 15) * 8;
            ushort hh = tobf(o);
            yhi[fi] = hh;
            ylo[fi] = tobf(o - frombf(hh));
        }
    }
}

extern "C" void kernel_launch(void* const* d_in, const int* in_sizes, int n_in,
                              void* d_out, int out_size, void* d_ws, size_t ws_size,
                              hipStream_t stream) {
    const float* x      = (const float*)d_in[0];
    const float* W_in   = (const float*)d_in[1];
    const float* conv_w = (const float*)d_in[2];
    const float* conv_b = (const float*)d_in[3];
    const float* A      = (const float*)d_in[4];
    const float* Bp     = (const float*)d_in[5];
    const float* Cp     = (const float*)d_in[6];
    const float* W_out  = (const float*)d_in[8];
    float* out = (float*)d_out;

    char* ws = (char*)d_ws;
    float* xp    = (float*)ws;                       // [0,32M): GEMM1 out / scan in
    // W_in i8 (dead after GEMM1; overwritten by yg):
    uchar* Wh8   = (uchar*)(ws + (32u << 20));       // [32,36M)
    uchar* Wl8   = (uchar*)(ws + (36u << 20));       // [36,40M)
    float* sW    = (float*)(ws + (40u << 20));       // 16KB
    // yg bf16 hi/lo (scan out, GEMM2 A):
    ushort* yghi = (ushort*)(ws + (32u << 20));      // [32,40M)
    ushort* yglo = (ushort*)(ws + (40u << 20));      // [40,48M)
    // W_out bf16 splits (after scan; xp dead):
    ushort* Wohi = (ushort*)ws;                      // [0,4M)
    ushort* Wolo = (ushort*)(ws + (4u << 20));       // [4,8M)
    float*  Prest = (float*)(ws + (8u << 20));       // [8,32M): split-K partials
    // x i8 + scale live in d_out (dead before GEMM2 writes out):
    uchar* xh8 = (uchar*)d_out;                      // [0,2M)
    uchar* xl8 = xh8 + (2u << 20);                   // [2,4M)
    float* sX  = (float*)(xh8 + (4u << 20));         // 8KB

    dim3 blk(256);
    quant_rows<<<dim3((NPROJ + MROWS) / 4), blk, 0, stream>>>(
        W_in, Wh8, Wl8, sW, NPROJ, x, xh8, xl8, sX);
    gemm1_i8<<<dim3(16, 16), dim3(512), 0, stream>>>(
        xh8, xl8, sX, Wh8, Wl8, sW, xp);
    scan_kernel<<<dim3(BSZ * NCHK * (INNER / 256)), blk, 0, stream>>>(
        xp, conv_w, conv_b, A, Bp, Cp, yghi, yglo);
    splitbf_frag<INNER><<<dim3((D_MODEL * INNER / 8) / 256), blk, 0, stream>>>(
        W_out, Wohi, Wolo, D_MODEL * INNER / 8);
    gemm_pipe<128, D_MODEL, INNER, 4, true, 2, 256>
        <<<dim3(8, 16, 4), dim3(256), 0, stream>>>(yghi, yglo, Wohi, Wolo, out, Prest);
    reduce_sk<<<dim3((MROWS * D_MODEL / 4) / 256), blk, 0, stream>>>(out, Prest);
}

// Round 18
// 100.128 us; speedup vs baseline: 1.6383x; 1.0454x over previous
//
#include <hip/hip_runtime.h>
#include <hip/hip_bf16.h>

#define D_MODEL 1024
#define INNER   2048
#define NPROJ   4096   // 2*INNER
#define BSZ     2
#define LSEQ    1024
#define MROWS   (BSZ*LSEQ)  // 2048

#define CHUNK 32
#define WARM  24
#define NCHK  (LSEQ / CHUNK)   // 32

using f32x4    = __attribute__((ext_vector_type(4))) float;
using i32x4    = __attribute__((ext_vector_type(4))) int;
using char16v  = __attribute__((ext_vector_type(16))) char;
typedef unsigned short ushort;
typedef unsigned char uchar;

#define MFMAI8(A,B,Cv) __builtin_amdgcn_mfma_i32_16x16x64_i8(A,B,Cv,0,0,0)

__device__ __forceinline__ void glds16(const void* g, void* l) {
    __builtin_amdgcn_global_load_lds((const __attribute__((address_space(1))) void*)g,
                                     (__attribute__((address_space(3))) void*)l, 16, 0, 0);
}

// ---------------------------------------------------------------------------
// Row-wise two-digit i8 quantization into 16x64 FRAGMENT-LINEAR subtiles.
// x ~ s*(h + l/256), s = rowmax/127. Subtile (rt,kt) = 16 rows x 64 k;
// lane holds 16 contiguous k-bytes per chunk. Two sources per launch.
// ---------------------------------------------------------------------------
template<int K>
__global__ __launch_bounds__(256) void quant2src(
    const float* __restrict__ S1, uchar* __restrict__ h1, uchar* __restrict__ l1,
    float* __restrict__ sc1, int R1,
    const float* __restrict__ S2, uchar* __restrict__ h2, uchar* __restrict__ l2,
    float* __restrict__ sc2)
{
    constexpr int CH = K / 1024;     // 16-elem chunks per lane
    constexpr int KT64 = K / 64;
    int gw = blockIdx.x * 4 + (threadIdx.x >> 6);
    int lane = threadIdx.x & 63;
    const float* src; uchar *dh, *dl; float* ss; int r;
    if (gw < R1) { r = gw;      src = S1 + (size_t)r * K; dh = h1; dl = l1; ss = sc1; }
    else         { r = gw - R1; src = S2 + (size_t)r * K; dh = h2; dl = l2; ss = sc2; }

    float v[16 * CH];
#pragma unroll
    for (int p = 0; p < 4 * CH; ++p) {
        float4 f = *reinterpret_cast<const float4*>(src + lane * 16 * CH + p * 4);
        v[p*4+0] = f.x; v[p*4+1] = f.y; v[p*4+2] = f.z; v[p*4+3] = f.w;
    }
    float mx = 0.f;
#pragma unroll
    for (int j = 0; j < 16 * CH; ++j) mx = fmaxf(mx, fabsf(v[j]));
#pragma unroll
    for (int off = 1; off < 64; off <<= 1) mx = fmaxf(mx, __shfl_xor(mx, off));
    float s1 = fmaxf(mx, 1e-20f) / 127.f;
    if (lane == 0) ss[r] = s1;
    float inv = 1.f / s1;
#pragma unroll
    for (int c = 0; c < CH; ++c) {
        char16v hb, lb;
#pragma unroll
        for (int j = 0; j < 16; ++j) {
            float t = v[c * 16 + j] * inv;
            float h = rintf(t);
            float l = rintf((t - h) * 256.f);
            l = fminf(fmaxf(l, -128.f), 127.f);
            hb[j] = (char)(int)h;
            lb[j] = (char)(int)l;
        }
        int gc = lane * CH + c;
        size_t byte = (((size_t)(r >> 4) * KT64 + (gc >> 2)) * 64
                       + ((gc & 3) << 4) + (r & 15)) * 16;
        *reinterpret_cast<i32x4*>(dh + byte) = *reinterpret_cast<const i32x4*>(&hb);
        *reinterpret_cast<i32x4*>(dl + byte) = *reinterpret_cast<const i32x4*>(&lb);
    }
}

// ---------------------------------------------------------------------------
// GEMM1 (in_proj) i8x3: C[2048,4096] = x * W_in^T (proven R17 kernel).
// 512 thr / 8 waves, BM=128 BN=256 BK=64, NT=16, NBUF=3, vmcnt(6).
// ---------------------------------------------------------------------------
__global__ __launch_bounds__(512, 1) void gemm1_i8(
    const uchar* __restrict__ Xh, const uchar* __restrict__ Xl, const float* __restrict__ sX,
    const uchar* __restrict__ Wh, const uchar* __restrict__ Wl, const float* __restrict__ sW,
    float* __restrict__ C)
{
    constexpr int KT64 = D_MODEL / 64;   // 16
    constexpr int NT = 16;
    __shared__ uchar Ah[3][8192], Al[3][8192];
    __shared__ uchar Bh[3][16384], Bl[3][16384];

    const int tid = threadIdx.x;
    const int wid = tid >> 6, lane = tid & 63;
    const int lm = lane & 15, lk = lane >> 4;

    constexpr int NTX = NPROJ / 256;
    constexpr int CPX = (NTX * (MROWS / 128)) / 8;
    int lin = blockIdx.y * NTX + blockIdx.x;
    int swz = (lin & 7) * CPX + (lin >> 3);
    const int m0 = (swz / NTX) * 128, n0 = (swz % NTX) * 256;
    const int wm = (wid >> 2) * 64, wn = (wid & 3) * 64;

    i32x4 acc1[4][4] = {};
    i32x4 acc2[4][4] = {};

    auto issueB = [&](const uchar* __restrict__ src, uchar* dst, int t, int ci) {
        int s = wid + ci * 8;
        const uchar* g = src + ((size_t)((n0 >> 4) + s) * KT64 + t) * 1024 + lane * 16;
        glds16(g, dst + s * 1024);
    };
    auto issueA = [&](const uchar* __restrict__ src, uchar* dst, int t) {
        const uchar* g = src + ((size_t)((m0 >> 4) + wid) * KT64 + t) * 1024 + lane * 16;
        glds16(g, dst + wid * 1024);
    };
    auto stageTile = [&](int t, int b) {
        issueB(Wh, &Bh[b][0], t, 0); issueB(Wh, &Bh[b][0], t, 1);
        issueB(Wl, &Bl[b][0], t, 0); issueB(Wl, &Bl[b][0], t, 1);
        issueA(Xh, &Ah[b][0], t);    issueA(Xl, &Al[b][0], t);
    };

    stageTile(0, 0);
    stageTile(1, 1);
    asm volatile("s_waitcnt vmcnt(6)" ::: "memory");
    __builtin_amdgcn_s_barrier();

    i32x4 ah[4], bh[4];
#pragma unroll
    for (int i = 0; i < 4; ++i)
        ah[i] = *reinterpret_cast<const i32x4*>(&Ah[0][((wm >> 4) + i) * 1024 + lane * 16]);
#pragma unroll
    for (int q = 0; q < 4; ++q)
        bh[q] = *reinterpret_cast<const i32x4*>(&Bh[0][((wn >> 4) + q) * 1024 + lane * 16]);

    int cur = 0;
    for (int t = 0; t < NT; ++t) {
        int nxt = cur + 1; if (nxt == 3) nxt = 0;
        int stg = cur + 2; if (stg >= 3) stg -= 3;
        const bool pf = (t + 2 < NT);
        i32x4 bl[4], al[4];

        asm volatile("s_waitcnt lgkmcnt(0)" ::: "memory");
        __builtin_amdgcn_sched_barrier(0);
        __builtin_amdgcn_s_setprio(1);
#pragma unroll
        for (int i = 0; i < 4; ++i)
#pragma unroll
            for (int q = 0; q < 4; ++q)
                acc1[i][q] = MFMAI8(ah[i], bh[q], acc1[i][q]);
        __builtin_amdgcn_s_setprio(0);
#pragma unroll
        for (int q = 0; q < 4; ++q)
            bl[q] = *reinterpret_cast<const i32x4*>(&Bl[cur][((wn >> 4) + q) * 1024 + lane * 16]);
        if (pf) {
            issueB(Wh, &Bh[stg][0], t + 2, 0);
            issueB(Wh, &Bh[stg][0], t + 2, 1);
        }

        asm volatile("s_waitcnt lgkmcnt(0)" ::: "memory");
        __builtin_amdgcn_sched_barrier(0);
        __builtin_amdgcn_s_setprio(1);
#pragma unroll
        for (int i = 0; i < 4; ++i)
#pragma unroll
            for (int q = 0; q < 4; ++q)
                acc2[i][q] = MFMAI8(ah[i], bl[q], acc2[i][q]);
        __builtin_amdgcn_s_setprio(0);
#pragma unroll
        for (int i = 0; i < 4; ++i)
            al[i] = *reinterpret_cast<const i32x4*>(&Al[cur][((wm >> 4) + i) * 1024 + lane * 16]);
        if (pf) {
            issueB(Wl, &Bl[stg][0], t + 2, 0);
            issueB(Wl, &Bl[stg][0], t + 2, 1);
        }
        __builtin_amdgcn_s_barrier();

        asm volatile("s_waitcnt lgkmcnt(0)" ::: "memory");
        __builtin_amdgcn_sched_barrier(0);
        __builtin_amdgcn_s_setprio(1);
#pragma unroll
        for (int i = 0; i < 4; ++i)
#pragma unroll
            for (int q = 0; q < 4; ++q)
                acc2[i][q] = MFMAI8(al[i], bh[q], acc2[i][q]);
        __builtin_amdgcn_s_setprio(0);
        if (pf) {
            issueA(Xh, &Ah[stg][0], t + 2);
            issueA(Xl, &Al[stg][0], t + 2);
        }
        if (pf) asm volatile("s_waitcnt vmcnt(6)" ::: "memory");
        else    asm volatile("s_waitcnt vmcnt(0)" ::: "memory");
        __builtin_amdgcn_s_barrier();

        if (t + 1 < NT) {
#pragma unroll
            for (int i = 0; i < 4; ++i)
                ah[i] = *reinterpret_cast<const i32x4*>(&Ah[nxt][((wm >> 4) + i) * 1024 + lane * 16]);
#pragma unroll
            for (int q = 0; q < 4; ++q)
                bh[q] = *reinterpret_cast<const i32x4*>(&Bh[nxt][((wn >> 4) + q) * 1024 + lane * 16]);
        }
        cur = nxt;
    }

#pragma unroll
    for (int i = 0; i < 4; ++i) {
        int r0 = m0 + wm + i * 16 + lk * 4;
        float4 s4 = *reinterpret_cast<const float4*>(&sX[r0]);
        float sa[4] = {s4.x, s4.y, s4.z, s4.w};
#pragma unroll
        for (int j = 0; j < 4; ++j) {
            int col = n0 + wn + j * 16 + lm;
            float sb = sW[col];
#pragma unroll
            for (int r = 0; r < 4; ++r) {
                float o = sa[r] * sb *
                    ((float)acc1[i][j][r] + (float)acc2[i][j][r] * 0.00390625f);
                C[(size_t)(r0 + r) * NPROJ + col] = o;
            }
        }
    }
}

// ---------------------------------------------------------------------------
// GEMM2 (out_proj) i8x3, split-K: C[2048,1024] = yg * W_out^T.
// BM=BN=128, 4 waves (2Mx2N), BK=64, NBUF=2 (64KB LDS -> 2 WGs/CU, R13 shape),
// SPLITK=4 (NT=8). kz=0 -> C0 (d_out), kz>0 -> Prest; reduce_sk sums.
// ---------------------------------------------------------------------------
__global__ __launch_bounds__(256, 2) void gemm2_i8(
    const uchar* __restrict__ Yh, const uchar* __restrict__ Yl, const float* __restrict__ sY,
    const uchar* __restrict__ Wh, const uchar* __restrict__ Wl, const float* __restrict__ sW,
    float* __restrict__ C0, float* __restrict__ Crest)
{
    constexpr int KT64 = INNER / 64;   // 32
    constexpr int SPLITK = 4;
    constexpr int NT = KT64 / SPLITK;  // 8
    __shared__ uchar Ah[2][8192], Al[2][8192];   // 128x64 i8
    __shared__ uchar Bh[2][8192], Bl[2][8192];

    const int tid = threadIdx.x;
    const int wid = tid >> 6, lane = tid & 63;
    const int lm = lane & 15, lk = lane >> 4;

    constexpr int NTX = D_MODEL / 128;       // 8
    constexpr int CPX = (NTX * (MROWS / 128)) / 8;
    int lin = blockIdx.y * NTX + blockIdx.x;
    int swz = (lin & 7) * CPX + (lin >> 3);
    const int m0 = (swz / NTX) * 128, n0 = (swz % NTX) * 128;
    const int t0 = blockIdx.z * NT;
    const int wm = (wid >> 1) * 64, wn = (wid & 1) * 64;

    i32x4 acc1[4][4] = {};
    i32x4 acc2[4][4] = {};

    auto issueB = [&](const uchar* __restrict__ src, uchar* dst, int tg) {
#pragma unroll
        for (int ci = 0; ci < 2; ++ci) {
            int s = wid + ci * 4;
            const uchar* g = src + ((size_t)((n0 >> 4) + s) * KT64 + tg) * 1024 + lane * 16;
            glds16(g, dst + s * 1024);
        }
    };
    auto issueA = [&](const uchar* __restrict__ src, uchar* dst, int tg) {
#pragma unroll
        for (int ci = 0; ci < 2; ++ci) {
            int s = wid + ci * 4;
            const uchar* g = src + ((size_t)((m0 >> 4) + s) * KT64 + tg) * 1024 + lane * 16;
            glds16(g, dst + s * 1024);
        }
    };
    auto stageTile = [&](int tg, int b) {
        issueB(Wh, &Bh[b][0], tg);
        issueB(Wl, &Bl[b][0], tg);
        issueA(Yh, &Ah[b][0], tg);
        issueA(Yl, &Al[b][0], tg);
    };

    stageTile(t0, 0);
    asm volatile("s_waitcnt vmcnt(0)" ::: "memory");
    __builtin_amdgcn_s_barrier();

    i32x4 ah[4], bh[4];
#pragma unroll
    for (int i = 0; i < 4; ++i)
        ah[i] = *reinterpret_cast<const i32x4*>(&Ah[0][((wm >> 4) + i) * 1024 + lane * 16]);
#pragma unroll
    for (int q = 0; q < 4; ++q)
        bh[q] = *reinterpret_cast<const i32x4*>(&Bh[0][((wn >> 4) + q) * 1024 + lane * 16]);

    int cur = 0;
    for (int t = 0; t < NT; ++t) {
        int nxt = cur ^ 1;
        const bool pf = (t + 1 < NT);
        i32x4 bl[4], al[4];

        asm volatile("s_waitcnt lgkmcnt(0)" ::: "memory");
        __builtin_amdgcn_sched_barrier(0);
        __builtin_amdgcn_s_setprio(1);
#pragma unroll
        for (int i = 0; i < 4; ++i)
#pragma unroll
            for (int q = 0; q < 4; ++q)
                acc1[i][q] = MFMAI8(ah[i], bh[q], acc1[i][q]);
        __builtin_amdgcn_s_setprio(0);
#pragma unroll
        for (int q = 0; q < 4; ++q)
            bl[q] = *reinterpret_cast<const i32x4*>(&Bl[cur][((wn >> 4) + q) * 1024 + lane * 16]);
        if (pf) issueB(Wh, &Bh[nxt][0], t0 + t + 1);

        asm volatile("s_waitcnt lgkmcnt(0)" ::: "memory");
        __builtin_amdgcn_sched_barrier(0);
        __builtin_amdgcn_s_setprio(1);
#pragma unroll
        for (int i = 0; i < 4; ++i)
#pragma unroll
            for (int q = 0; q < 4; ++q)
                acc2[i][q] = MFMAI8(ah[i], bl[q], acc2[i][q]);
        __builtin_amdgcn_s_setprio(0);
#pragma unroll
        for (int i = 0; i < 4; ++i)
            al[i] = *reinterpret_cast<const i32x4*>(&Al[cur][((wm >> 4) + i) * 1024 + lane * 16]);
        if (pf) issueB(Wl, &Bl[nxt][0], t0 + t + 1);
        __builtin_amdgcn_s_barrier();

        asm volatile("s_waitcnt lgkmcnt(0)" ::: "memory");
        __builtin_amdgcn_sched_barrier(0);
        __builtin_amdgcn_s_setprio(1);
#pragma unroll
        for (int i = 0; i < 4; ++i)
#pragma unroll
            for (int q = 0; q < 4; ++q)
                acc2[i][q] = MFMAI8(al[i], bh[q], acc2[i][q]);
        __builtin_amdgcn_s_setprio(0);
        if (pf) {
            issueA(Yh, &Ah[nxt][0], t0 + t + 1);
            issueA(Yl, &Al[nxt][0], t0 + t + 1);
        }
        asm volatile("s_waitcnt vmcnt(0)" ::: "memory");
        __builtin_amdgcn_s_barrier();

        if (t + 1 < NT) {
#pragma unroll
            for (int i = 0; i < 4; ++i)
                ah[i] = *reinterpret_cast<const i32x4*>(&Ah[nxt][((wm >> 4) + i) * 1024 + lane * 16]);
#pragma unroll
            for (int q = 0; q < 4; ++q)
                bh[q] = *reinterpret_cast<const i32x4*>(&Bh[nxt][((wn >> 4) + q) * 1024 + lane * 16]);
        }
        cur = nxt;
    }

    int kz = blockIdx.z;
    float* C = (kz == 0) ? C0 : (Crest + (size_t)(kz - 1) * MROWS * D_MODEL);
#pragma unroll
    for (int i = 0; i < 4; ++i) {
        int r0 = m0 + wm + i * 16 + lk * 4;
        float4 s4 = *reinterpret_cast<const float4*>(&sY[r0]);
        float sa[4] = {s4.x, s4.y, s4.z, s4.w};
#pragma unroll
        for (int j = 0; j < 4; ++j) {
            int col = n0 + wn + j * 16 + lm;
            float sb = sW[col];
#pragma unroll
            for (int r = 0; r < 4; ++r) {
                float o = sa[r] * sb *
                    ((float)acc1[i][j][r] + (float)acc2[i][j][r] * 0.00390625f);
                C[(size_t)(r0 + r) * D_MODEL + col] = o;
            }
        }
    }
}

// out += sum of 3 partials (out already holds partial 0)
__global__ __launch_bounds__(256) void reduce_sk(float* __restrict__ out,
                                                 const float* __restrict__ rest) {
    constexpr size_t MN = (size_t)MROWS * D_MODEL;
    size_t i = ((size_t)blockIdx.x * 256 + threadIdx.x) * 4;
    f32x4 a = *reinterpret_cast<const f32x4*>(&out[i]);
    f32x4 b = *reinterpret_cast<const f32x4*>(&rest[i]);
    f32x4 c = *reinterpret_cast<const f32x4*>(&rest[MN + i]);
    f32x4 d = *reinterpret_cast<const f32x4*>(&rest[2 * MN + i]);
    *reinterpret_cast<f32x4*>(&out[i]) = (a + b) + (c + d);
}

// Chunk-parallel fused conv + sigmoid + scan + gate; emits yg as plain f32
// row-major (R, n) for the quantization pass.
__global__ __launch_bounds__(256) void scan_kernel(
    const float* __restrict__ xp,
    const float* __restrict__ conv_w, const float* __restrict__ conv_b,
    const float* __restrict__ Aa, const float* __restrict__ Bp, const float* __restrict__ Cp,
    float* __restrict__ yg)
{
    const int NB = INNER / 256;  // 8
    int tid = threadIdx.x;
    int bi = blockIdx.x;
    int b  = bi / (NCHK * NB);
    int r  = bi % (NCHK * NB);
    int ch = r / NB;
    int n  = (r % NB) * 256 + tid;

    float4 w = *reinterpret_cast<const float4*>(&conv_w[n * 4]);
    float cb = conv_b[n];
    float An[16], Bn[16], Cn[16], st[16];
#pragma unroll
    for (int i = 0; i < 16; i += 4) {
        float4 va = *reinterpret_cast<const float4*>(&Aa[n * 16 + i]);
        float4 vb = *reinterpret_cast<const float4*>(&Bp[n * 16 + i]);
        float4 vc = *reinterpret_cast<const float4*>(&Cp[n * 16 + i]);
        An[i]=va.x; An[i+1]=va.y; An[i+2]=va.z; An[i+3]=va.w;
        Bn[i]=vb.x; Bn[i+1]=vb.y; Bn[i+2]=vb.z; Bn[i+3]=vb.w;
        Cn[i]=vc.x; Cn[i+1]=vc.y; Cn[i+2]=vc.z; Cn[i+3]=vc.w;
    }
#pragma unroll
    for (int s = 0; s < 16; ++s) st[s] = 0.f;

    int out0 = ch * CHUNK;
    int lstart = (out0 >= WARM) ? (out0 - WARM) : 0;
    float u0 = 0.f, u1 = 0.f, u2 = 0.f;
    const float* xb = xp + (size_t)b * LSEQ * NPROJ;

    for (int l = lstart; l < out0; l += 8) {
        float uv[8];
#pragma unroll
        for (int i = 0; i < 8; ++i)
            uv[i] = xb[(size_t)(l + i) * NPROJ + 2 * n];
#pragma unroll
        for (int i = 0; i < 8; ++i) {
            float ul = uv[i];
            float xc = cb + w.x * u0 + w.y * u1 + w.z * u2 + w.w * ul;
            u0 = u1; u1 = u2; u2 = ul;
            float d = 1.f / (1.f + __expf(-xc));
            float dxc = d * xc;
#pragma unroll
            for (int s = 0; s < 16; ++s)
                st[s] = (An[s] * d) * st[s] + Bn[s] * dxc;
        }
    }
    for (int lt = 0; lt < CHUNK; lt += 8) {
        float uv[8], gv[8];
#pragma unroll
        for (int i = 0; i < 8; ++i) {
            float2 ug = *reinterpret_cast<const float2*>(
                &xb[(size_t)(out0 + lt + i) * NPROJ + 2 * n]);
            uv[i] = ug.x; gv[i] = ug.y;
        }
#pragma unroll
        for (int i = 0; i < 8; ++i) {
            float ul = uv[i];
            float xc = cb + w.x * u0 + w.y * u1 + w.z * u2 + w.w * ul;
            u0 = u1; u1 = u2; u2 = ul;
            float d = 1.f / (1.f + __expf(-xc));
            float dxc = d * xc;
            float y0 = 0.f, y1 = 0.f, y2 = 0.f, y3 = 0.f;
#pragma unroll
            for (int s = 0; s < 16; s += 4) {
                st[s + 0] = (An[s + 0] * d) * st[s + 0] + Bn[s + 0] * dxc;
                st[s + 1] = (An[s + 1] * d) * st[s + 1] + Bn[s + 1] * dxc;
                st[s + 2] = (An[s + 2] * d) * st[s + 2] + Bn[s + 2] * dxc;
                st[s + 3] = (An[s + 3] * d) * st[s + 3] + Bn[s + 3] * dxc;
                y0 += st[s + 0] * Cn[s + 0];
                y1 += st[s + 1] * Cn[s + 1];
                y2 += st[s + 2] * Cn[s + 2];
                y3 += st[s + 3] * Cn[s + 3];
            }
            float y = (y0 + y1) + (y2 + y3);
            float g = 1.f / (1.f + __expf(-gv[i]));
            int R = b * LSEQ + out0 + lt + i;
            yg[(size_t)R * INNER + n] = y * g;
        }
    }
}

extern "C" void kernel_launch(void* const* d_in, const int* in_sizes, int n_in,
                              void* d_out, int out_size, void* d_ws, size_t ws_size,
                              hipStream_t stream) {
    const float* x      = (const float*)d_in[0];
    const float* W_in   = (const float*)d_in[1];
    const float* conv_w = (const float*)d_in[2];
    const float* conv_b = (const float*)d_in[3];
    const float* A      = (const float*)d_in[4];
    const float* Bp     = (const float*)d_in[5];
    const float* Cp     = (const float*)d_in[6];
    const float* W_out  = (const float*)d_in[8];
    float* out = (float*)d_out;

    char* ws = (char*)d_ws;
    // timeline: [quant1] -> [gemm1: reads Wh8/Wl8/sW + x-i8(d_out), writes xp]
    //           -> [scan: reads xp, writes yg] -> [quant2: reads yg/W_out,
    //           writes yg-i8 + wo-i8] -> [gemm2: writes out + Prest] -> [reduce]
    float* xp    = (float*)ws;                       // [0,32M) gemm1 out / scan in
    uchar* Wh8   = (uchar*)(ws + (32u << 20));       // [32,36M) W_in i8 hi
    uchar* Wl8   = (uchar*)(ws + (36u << 20));       // [36,40M) W_in i8 lo
    float* sW    = (float*)(ws + (40u << 20));       // 16KB
    float* yg    = (float*)(ws + (32u << 20));       // [32,48M) scan out (after gemm1)
    uchar* ygh8  = (uchar*)ws;                       // [0,4M)  (xp dead after scan)
    uchar* ygl8  = (uchar*)(ws + (4u << 20));        // [4,8M)
    float* Prest = (float*)(ws + (8u << 20));        // [8,32M) split-K partials 1..3
    uchar* woh8  = (uchar*)(ws + (48u << 20));       // [48,50M)
    uchar* wol8  = (uchar*)(ws + (50u << 20));       // [50,52M)
    float* sY    = (float*)(ws + (52u << 20));       // 8KB
    float* sWo   = (float*)(ws + (52u << 20) + (16u << 10));  // 4KB
    // x i8 + scale live in d_out (consumed by gemm1; d_out rewritten by gemm2)
    uchar* xh8 = (uchar*)d_out;                      // [0,2M)
    uchar* xl8 = xh8 + (2u << 20);                   // [2,4M)
    float* sX  = (float*)(xh8 + (4u << 20));         // 8KB

    dim3 blk(256);
    quant2src<D_MODEL><<<dim3((NPROJ + MROWS) / 4), blk, 0, stream>>>(
        W_in, Wh8, Wl8, sW, NPROJ, x, xh8, xl8, sX);
    gemm1_i8<<<dim3(16, 16), dim3(512), 0, stream>>>(
        xh8, xl8, sX, Wh8, Wl8, sW, xp);
    scan_kernel<<<dim3(BSZ * NCHK * (INNER / 256)), blk, 0, stream>>>(
        xp, conv_w, conv_b, A, Bp, Cp, yg);
    quant2src<INNER><<<dim3((MROWS + D_MODEL) / 4), blk, 0, stream>>>(
        yg, ygh8, ygl8, sY, MROWS, W_out, woh8, wol8, sWo);
    gemm2_i8<<<dim3(8, 16, 4), blk, 0, stream>>>(
        ygh8, ygl8, sY, woh8, wol8, sWo, out, Prest);
    reduce_sk<<<dim3((MROWS * D_MODEL / 4) / 256), blk, 0, stream>>>(out, Prest);
}

// Round 19
// 99.672 us; speedup vs baseline: 1.6458x; 1.0046x over previous
//
#include <hip/hip_runtime.h>
#include <hip/hip_bf16.h>

#define D_MODEL 1024
#define INNER   2048
#define NPROJ   4096   // 2*INNER
#define BSZ     2
#define LSEQ    1024
#define MROWS   (BSZ*LSEQ)  // 2048

#define CHUNK 32
#define WARM  24
#define NCHK  (LSEQ / CHUNK)   // 32

using f32x4    = __attribute__((ext_vector_type(4))) float;
using i32x4    = __attribute__((ext_vector_type(4))) int;
using char16v  = __attribute__((ext_vector_type(16))) char;
typedef unsigned short ushort;
typedef unsigned char uchar;

#define MFMAI8(A,B,Cv) __builtin_amdgcn_mfma_i32_16x16x64_i8(A,B,Cv,0,0,0)

__device__ __forceinline__ void glds16(const void* g, void* l) {
    __builtin_amdgcn_global_load_lds((const __attribute__((address_space(1))) void*)g,
                                     (__attribute__((address_space(3))) void*)l, 16, 0, 0);
}

// ---------------------------------------------------------------------------
// Row-wise two-digit i8 quantization into 16x64 FRAGMENT-LINEAR subtiles.
// x ~ s*(h + l/256), s = rowmax/127. Subtile (rt,kt) = 16 rows x 64 k;
// lane holds 16 contiguous k-bytes per chunk. Two sources per launch.
// ---------------------------------------------------------------------------
template<int K>
__global__ __launch_bounds__(256) void quant2src(
    const float* __restrict__ S1, uchar* __restrict__ h1, uchar* __restrict__ l1,
    float* __restrict__ sc1, int R1,
    const float* __restrict__ S2, uchar* __restrict__ h2, uchar* __restrict__ l2,
    float* __restrict__ sc2)
{
    constexpr int CH = K / 1024;     // 16-elem chunks per lane
    constexpr int KT64 = K / 64;
    int gw = blockIdx.x * 4 + (threadIdx.x >> 6);
    int lane = threadIdx.x & 63;
    const float* src; uchar *dh, *dl; float* ss; int r;
    if (gw < R1) { r = gw;      src = S1 + (size_t)r * K; dh = h1; dl = l1; ss = sc1; }
    else         { r = gw - R1; src = S2 + (size_t)r * K; dh = h2; dl = l2; ss = sc2; }

    float v[16 * CH];
#pragma unroll
    for (int p = 0; p < 4 * CH; ++p) {
        float4 f = *reinterpret_cast<const float4*>(src + lane * 16 * CH + p * 4);
        v[p*4+0] = f.x; v[p*4+1] = f.y; v[p*4+2] = f.z; v[p*4+3] = f.w;
    }
    float mx = 0.f;
#pragma unroll
    for (int j = 0; j < 16 * CH; ++j) mx = fmaxf(mx, fabsf(v[j]));
#pragma unroll
    for (int off = 1; off < 64; off <<= 1) mx = fmaxf(mx, __shfl_xor(mx, off));
    float s1 = fmaxf(mx, 1e-20f) / 127.f;
    if (lane == 0) ss[r] = s1;
    float inv = 1.f / s1;
#pragma unroll
    for (int c = 0; c < CH; ++c) {
        char16v hb, lb;
#pragma unroll
        for (int j = 0; j < 16; ++j) {
            float t = v[c * 16 + j] * inv;
            float h = rintf(t);
            float l = rintf((t - h) * 256.f);
            l = fminf(fmaxf(l, -128.f), 127.f);
            hb[j] = (char)(int)h;
            lb[j] = (char)(int)l;
        }
        int gc = lane * CH + c;
        size_t byte = (((size_t)(r >> 4) * KT64 + (gc >> 2)) * 64
                       + ((gc & 3) << 4) + (r & 15)) * 16;
        *reinterpret_cast<i32x4*>(dh + byte) = *reinterpret_cast<const i32x4*>(&hb);
        *reinterpret_cast<i32x4*>(dl + byte) = *reinterpret_cast<const i32x4*>(&lb);
    }
}

// ---------------------------------------------------------------------------
// Unified i8x3 GEMM: C[MROWS,NCOL] = A * B^T, A/B pre-quantized two-digit i8.
// BM=BN=128, 4 waves (2Mx2N, wave 64x64), BK=64, NBUF=2 -> 64KB LDS ->
// 2 WGs/CU (co-resident WGs hide each other's tile-boundary drains, m114).
// Per tile: R1{8 MFMA hh; read bl; issue Bh'} R2{8 MFMA hl; read al; issue
// Bl'} BAR R3{8 MFMA lh; issue A'; vmcnt(0)} BAR R4{read next ah,bh}.
// C = sA[r]*sB[c]*(acc1 + acc2/256). SPLITK>1: kz>0 writes Crest partials.
// ---------------------------------------------------------------------------
template<int NCOL, int K, int SPLITK, bool PARTIAL>
__global__ __launch_bounds__(256, 2) void gemm_i8(
    const uchar* __restrict__ Ahg, const uchar* __restrict__ Alg, const float* __restrict__ sA,
    const uchar* __restrict__ Bhg, const uchar* __restrict__ Blg, const float* __restrict__ sB,
    float* __restrict__ C0, float* __restrict__ Crest)
{
    constexpr int KT64 = K / 64;
    constexpr int NT = KT64 / SPLITK;
    __shared__ uchar Ah[2][8192], Al[2][8192];   // 128x64 i8
    __shared__ uchar Bh[2][8192], Bl[2][8192];

    const int tid = threadIdx.x;
    const int wid = tid >> 6, lane = tid & 63;
    const int lm = lane & 15, lk = lane >> 4;

    constexpr int NTX = NCOL / 128;
    constexpr int CPX = (NTX * (MROWS / 128)) / 8;
    int lin = blockIdx.y * NTX + blockIdx.x;
    int swz = (lin & 7) * CPX + (lin >> 3);
    const int m0 = (swz / NTX) * 128, n0 = (swz % NTX) * 128;
    const int t0 = (SPLITK > 1 ? blockIdx.z : 0) * NT;
    const int wm = (wid >> 1) * 64, wn = (wid & 1) * 64;

    i32x4 acc1[4][4] = {};
    i32x4 acc2[4][4] = {};

    auto issueB = [&](const uchar* __restrict__ src, uchar* dst, int tg) {
#pragma unroll
        for (int ci = 0; ci < 2; ++ci) {
            int s = wid + ci * 4;
            const uchar* g = src + ((size_t)((n0 >> 4) + s) * KT64 + tg) * 1024 + lane * 16;
            glds16(g, dst + s * 1024);
        }
    };
    auto issueA = [&](const uchar* __restrict__ src, uchar* dst, int tg) {
#pragma unroll
        for (int ci = 0; ci < 2; ++ci) {
            int s = wid + ci * 4;
            const uchar* g = src + ((size_t)((m0 >> 4) + s) * KT64 + tg) * 1024 + lane * 16;
            glds16(g, dst + s * 1024);
        }
    };
    auto stageTile = [&](int tg, int b) {
        issueB(Bhg, &Bh[b][0], tg);
        issueB(Blg, &Bl[b][0], tg);
        issueA(Ahg, &Ah[b][0], tg);
        issueA(Alg, &Al[b][0], tg);
    };

    stageTile(t0, 0);
    asm volatile("s_waitcnt vmcnt(0)" ::: "memory");
    __builtin_amdgcn_s_barrier();

    i32x4 ah[4], bh[4];
#pragma unroll
    for (int i = 0; i < 4; ++i)
        ah[i] = *reinterpret_cast<const i32x4*>(&Ah[0][((wm >> 4) + i) * 1024 + lane * 16]);
#pragma unroll
    for (int q = 0; q < 4; ++q)
        bh[q] = *reinterpret_cast<const i32x4*>(&Bh[0][((wn >> 4) + q) * 1024 + lane * 16]);

    int cur = 0;
    for (int t = 0; t < NT; ++t) {
        int nxt = cur ^ 1;
        const bool pf = (t + 1 < NT);
        i32x4 bl[4], al[4];

        // ---- R1: hh MFMA -> acc1; read bl(cur); issue Bh(t+1) ----
        asm volatile("s_waitcnt lgkmcnt(0)" ::: "memory");
        __builtin_amdgcn_sched_barrier(0);
        __builtin_amdgcn_s_setprio(1);
#pragma unroll
        for (int i = 0; i < 4; ++i)
#pragma unroll
            for (int q = 0; q < 4; ++q)
                acc1[i][q] = MFMAI8(ah[i], bh[q], acc1[i][q]);
        __builtin_amdgcn_s_setprio(0);
#pragma unroll
        for (int q = 0; q < 4; ++q)
            bl[q] = *reinterpret_cast<const i32x4*>(&Bl[cur][((wn >> 4) + q) * 1024 + lane * 16]);
        if (pf) issueB(Bhg, &Bh[nxt][0], t0 + t + 1);

        // ---- R2: hl MFMA -> acc2; read al(cur); issue Bl(t+1) ----
        asm volatile("s_waitcnt lgkmcnt(0)" ::: "memory");
        __builtin_amdgcn_sched_barrier(0);
        __builtin_amdgcn_s_setprio(1);
#pragma unroll
        for (int i = 0; i < 4; ++i)
#pragma unroll
            for (int q = 0; q < 4; ++q)
                acc2[i][q] = MFMAI8(ah[i], bl[q], acc2[i][q]);
        __builtin_amdgcn_s_setprio(0);
#pragma unroll
        for (int i = 0; i < 4; ++i)
            al[i] = *reinterpret_cast<const i32x4*>(&Al[cur][((wm >> 4) + i) * 1024 + lane * 16]);
        if (pf) issueB(Blg, &Bl[nxt][0], t0 + t + 1);
        __builtin_amdgcn_s_barrier();

        // ---- R3: lh MFMA -> acc2; issue A(t+1); drain ----
        asm volatile("s_waitcnt lgkmcnt(0)" ::: "memory");
        __builtin_amdgcn_sched_barrier(0);
        __builtin_amdgcn_s_setprio(1);
#pragma unroll
        for (int i = 0; i < 4; ++i)
#pragma unroll
            for (int q = 0; q < 4; ++q)
                acc2[i][q] = MFMAI8(al[i], bh[q], acc2[i][q]);
        __builtin_amdgcn_s_setprio(0);
        if (pf) {
            issueA(Ahg, &Ah[nxt][0], t0 + t + 1);
            issueA(Alg, &Al[nxt][0], t0 + t + 1);
        }
        asm volatile("s_waitcnt vmcnt(0)" ::: "memory");
        __builtin_amdgcn_s_barrier();

        // ---- R4: read next tile's hh frags ----
        if (t + 1 < NT) {
#pragma unroll
            for (int i = 0; i < 4; ++i)
                ah[i] = *reinterpret_cast<const i32x4*>(&Ah[nxt][((wm >> 4) + i) * 1024 + lane * 16]);
#pragma unroll
            for (int q = 0; q < 4; ++q)
                bh[q] = *reinterpret_cast<const i32x4*>(&Bh[nxt][((wn >> 4) + q) * 1024 + lane * 16]);
        }
        cur = nxt;
    }

    float* C = C0;
    if constexpr (PARTIAL) {
        int kz = blockIdx.z;
        if (kz != 0) C = Crest + (size_t)(kz - 1) * MROWS * NCOL;
    }
#pragma unroll
    for (int i = 0; i < 4; ++i) {
        int r0 = m0 + wm + i * 16 + lk * 4;
        float4 s4 = *reinterpret_cast<const float4*>(&sA[r0]);
        float sa[4] = {s4.x, s4.y, s4.z, s4.w};
#pragma unroll
        for (int j = 0; j < 4; ++j) {
            int col = n0 + wn + j * 16 + lm;
            float sb = sB[col];
#pragma unroll
            for (int r = 0; r < 4; ++r) {
                float o = sa[r] * sb *
                    ((float)acc1[i][j][r] + (float)acc2[i][j][r] * 0.00390625f);
                C[(size_t)(r0 + r) * NCOL + col] = o;
            }
        }
    }
}

// out += sum of 3 partials (out already holds partial 0)
__global__ __launch_bounds__(256) void reduce_sk(float* __restrict__ out,
                                                 const float* __restrict__ rest) {
    constexpr size_t MN = (size_t)MROWS * D_MODEL;
    size_t i = ((size_t)blockIdx.x * 256 + threadIdx.x) * 4;
    f32x4 a = *reinterpret_cast<const f32x4*>(&out[i]);
    f32x4 b = *reinterpret_cast<const f32x4*>(&rest[i]);
    f32x4 c = *reinterpret_cast<const f32x4*>(&rest[MN + i]);
    f32x4 d = *reinterpret_cast<const f32x4*>(&rest[2 * MN + i]);
    *reinterpret_cast<f32x4*>(&out[i]) = (a + b) + (c + d);
}

// Chunk-parallel fused conv + sigmoid + scan + gate; emits yg as plain f32
// row-major (R, n) for the quantization pass.
__global__ __launch_bounds__(256) void scan_kernel(
    const float* __restrict__ xp,
    const float* __restrict__ conv_w, const float* __restrict__ conv_b,
    const float* __restrict__ Aa, const float* __restrict__ Bp, const float* __restrict__ Cp,
    float* __restrict__ yg)
{
    const int NB = INNER / 256;  // 8
    int tid = threadIdx.x;
    int bi = blockIdx.x;
    int b  = bi / (NCHK * NB);
    int r  = bi % (NCHK * NB);
    int ch = r / NB;
    int n  = (r % NB) * 256 + tid;

    float4 w = *reinterpret_cast<const float4*>(&conv_w[n * 4]);
    float cb = conv_b[n];
    float An[16], Bn[16], Cn[16], st[16];
#pragma unroll
    for (int i = 0; i < 16; i += 4) {
        float4 va = *reinterpret_cast<const float4*>(&Aa[n * 16 + i]);
        float4 vb = *reinterpret_cast<const float4*>(&Bp[n * 16 + i]);
        float4 vc = *reinterpret_cast<const float4*>(&Cp[n * 16 + i]);
        An[i]=va.x; An[i+1]=va.y; An[i+2]=va.z; An[i+3]=va.w;
        Bn[i]=vb.x; Bn[i+1]=vb.y; Bn[i+2]=vb.z; Bn[i+3]=vb.w;
        Cn[i]=vc.x; Cn[i+1]=vc.y; Cn[i+2]=vc.z; Cn[i+3]=vc.w;
    }
#pragma unroll
    for (int s = 0; s < 16; ++s) st[s] = 0.f;

    int out0 = ch * CHUNK;
    int lstart = (out0 >= WARM) ? (out0 - WARM) : 0;
    float u0 = 0.f, u1 = 0.f, u2 = 0.f;
    const float* xb = xp + (size_t)b * LSEQ * NPROJ;

    for (int l = lstart; l < out0; l += 8) {
        float uv[8];
#pragma unroll
        for (int i = 0; i < 8; ++i)
            uv[i] = xb[(size_t)(l + i) * NPROJ + 2 * n];
#pragma unroll
        for (int i = 0; i < 8; ++i) {
            float ul = uv[i];
            float xc = cb + w.x * u0 + w.y * u1 + w.z * u2 + w.w * ul;
            u0 = u1; u1 = u2; u2 = ul;
            float d = 1.f / (1.f + __expf(-xc));
            float dxc = d * xc;
#pragma unroll
            for (int s = 0; s < 16; ++s)
                st[s] = (An[s] * d) * st[s] + Bn[s] * dxc;
        }
    }
    for (int lt = 0; lt < CHUNK; lt += 8) {
        float uv[8], gv[8];
#pragma unroll
        for (int i = 0; i < 8; ++i) {
            float2 ug = *reinterpret_cast<const float2*>(
                &xb[(size_t)(out0 + lt + i) * NPROJ + 2 * n]);
            uv[i] = ug.x; gv[i] = ug.y;
        }
#pragma unroll
        for (int i = 0; i < 8; ++i) {
            float ul = uv[i];
            float xc = cb + w.x * u0 + w.y * u1 + w.z * u2 + w.w * ul;
            u0 = u1; u1 = u2; u2 = ul;
            float d = 1.f / (1.f + __expf(-xc));
            float dxc = d * xc;
            float y0 = 0.f, y1 = 0.f, y2 = 0.f, y3 = 0.f;
#pragma unroll
            for (int s = 0; s < 16; s += 4) {
                st[s + 0] = (An[s + 0] * d) * st[s + 0] + Bn[s + 0] * dxc;
                st[s + 1] = (An[s + 1] * d) * st[s + 1] + Bn[s + 1] * dxc;
                st[s + 2] = (An[s + 2] * d) * st[s + 2] + Bn[s + 2] * dxc;
                st[s + 3] = (An[s + 3] * d) * st[s + 3] + Bn[s + 3] * dxc;
                y0 += st[s + 0] * Cn[s + 0];
                y1 += st[s + 1] * Cn[s + 1];
                y2 += st[s + 2] * Cn[s + 2];
                y3 += st[s + 3] * Cn[s + 3];
            }
            float y = (y0 + y1) + (y2 + y3);
            float g = 1.f / (1.f + __expf(-gv[i]));
            int R = b * LSEQ + out0 + lt + i;
            yg[(size_t)R * INNER + n] = y * g;
        }
    }
}

extern "C" void kernel_launch(void* const* d_in, const int* in_sizes, int n_in,
                              void* d_out, int out_size, void* d_ws, size_t ws_size,
                              hipStream_t stream) {
    const float* x      = (const float*)d_in[0];
    const float* W_in   = (const float*)d_in[1];
    const float* conv_w = (const float*)d_in[2];
    const float* conv_b = (const float*)d_in[3];
    const float* A      = (const float*)d_in[4];
    const float* Bp     = (const float*)d_in[5];
    const float* Cp     = (const float*)d_in[6];
    const float* W_out  = (const float*)d_in[8];
    float* out = (float*)d_out;

    char* ws = (char*)d_ws;
    float* xp    = (float*)ws;                       // [0,32M) gemm1 out / scan in
    uchar* Wh8   = (uchar*)(ws + (32u << 20));       // [32,36M) W_in i8 hi
    uchar* Wl8   = (uchar*)(ws + (36u << 20));       // [36,40M) W_in i8 lo
    float* sW    = (float*)(ws + (40u << 20));       // 16KB
    float* yg    = (float*)(ws + (32u << 20));       // [32,48M) scan out (after gemm1)
    uchar* ygh8  = (uchar*)ws;                       // [0,4M)  (xp dead after scan)
    uchar* ygl8  = (uchar*)(ws + (4u << 20));        // [4,8M)
    float* Prest = (float*)(ws + (8u << 20));        // [8,32M) split-K partials 1..3
    uchar* woh8  = (uchar*)(ws + (48u << 20));       // [48,50M)
    uchar* wol8  = (uchar*)(ws + (50u << 20));       // [50,52M)
    float* sY    = (float*)(ws + (52u << 20));       // 8KB
    float* sWo   = (float*)(ws + (52u << 20) + (16u << 10));  // 4KB
    uchar* xh8 = (uchar*)d_out;                      // [0,2M)  x i8 in d_out
    uchar* xl8 = xh8 + (2u << 20);                   // [2,4M)
    float* sX  = (float*)(xh8 + (4u << 20));         // 8KB

    dim3 blk(256);
    quant2src<D_MODEL><<<dim3((NPROJ + MROWS) / 4), blk, 0, stream>>>(
        W_in, Wh8, Wl8, sW, NPROJ, x, xh8, xl8, sX);
    gemm_i8<NPROJ, D_MODEL, 1, false><<<dim3(32, 16), blk, 0, stream>>>(
        xh8, xl8, sX, Wh8, Wl8, sW, xp, nullptr);
    scan_kernel<<<dim3(BSZ * NCHK * (INNER / 256)), blk, 0, stream>>>(
        xp, conv_w, conv_b, A, Bp, Cp, yg);
    quant2src<INNER><<<dim3((MROWS + D_MODEL) / 4), blk, 0, stream>>>(
        yg, ygh8, ygl8, sY, MROWS, W_out, woh8, wol8, sWo);
    gemm_i8<D_MODEL, INNER, 4, true><<<dim3(8, 16, 4), blk, 0, stream>>>(
        ygh8, ygl8, sY, woh8, wol8, sWo, out, Prest);
    reduce_sk<<<dim3((MROWS * D_MODEL / 4) / 256), blk, 0, stream>>>(out, Prest);
}